// Round 1
// 797.853 us; speedup vs baseline: 1.2220x; 1.2220x over previous
//
#include <hip/hip_runtime.h>
#include <hip/hip_bf16.h>
#include <cstddef>

#define B_   4
#define L_   2048
#define DM   1024
#define DI   2048
#define NST  16
#define DTR  64        // (1024+15)//16 = 64
#define NBC  96        // DTR + 2*NST
#define NTOK 8192      // B_*L_

using bf16 = __hip_bfloat16;
typedef __attribute__((ext_vector_type(8))) short bf16x8;
typedef __attribute__((ext_vector_type(4))) short s16x4;
typedef __attribute__((ext_vector_type(4))) float f32x4;

__device__ __forceinline__ float bf2f(short s) {
  unsigned u = ((unsigned)(unsigned short)s) << 16;
  float f; __builtin_memcpy(&f, &u, 4); return f;
}
__device__ __forceinline__ short f2bs(float f) {
  __hip_bfloat16 h = __float2bfloat16(f);
  short s; __builtin_memcpy(&s, &h, 2); return s;
}
__device__ __forceinline__ float sigmoidf_fast(float x) {
  return 1.f / (1.f + __expf(-x));
}

// cross-lane xor shuffles for the 16-state butterfly reduce
__device__ __forceinline__ float swz_xor8(float x) {
  return __builtin_bit_cast(float,
    __builtin_amdgcn_ds_swizzle(__builtin_bit_cast(int, x), 0x201F)); // lane ^= 8
}
__device__ __forceinline__ float swz_xor4(float x) {
  return __builtin_bit_cast(float,
    __builtin_amdgcn_ds_swizzle(__builtin_bit_cast(int, x), 0x101F)); // lane ^= 4
}
template<int CTRL>
__device__ __forceinline__ float qperm(float x) {  // DPP quad_perm, full VALU rate
  return __builtin_bit_cast(float,
    __builtin_amdgcn_update_dpp(0, __builtin_bit_cast(int, x), CTRL, 0xf, 0xf, false));
}

// ---------------------------------------------------------------------------
// transpose f32 in -> bf16 out, zero-pad: out[c][r] = (r<R&&c<Cc) ? in[r*lin+c] : 0
// ---------------------------------------------------------------------------
__global__ __launch_bounds__(256)
void transpose_f2b(const float* __restrict__ in, short* __restrict__ out,
                   int R, int Cc, int lin, int lout)
{
  __shared__ short t[32][33];
  const int r0 = blockIdx.x * 32, c0 = blockIdx.y * 32;
  const int tx = threadIdx.x, ty = threadIdx.y;
#pragma unroll
  for (int i = 0; i < 4; i++) {
    int r = r0 + ty + i * 8;
    int c = c0 + tx;
    short v = 0;
    if (r < R && c < Cc) v = f2bs(in[(size_t)r * lin + c]);
    t[ty + i * 8][tx] = v;
  }
  __syncthreads();
#pragma unroll
  for (int i = 0; i < 4; i++) {
    int c = c0 + ty + i * 8;
    int r = r0 + tx;
    if (c < Cc && r < lout) out[(size_t)c * lout + r] = t[tx][ty + i * 8];
  }
}

// ---------------------------------------------------------------------------
// bf16 MFMA GEMM, C[M x N] = A[M x K] * Bt[N x K]^T.  128x128 tile, BK=32,
// 4 waves each 64x64 (4x4 of 16x16x32 MFMA).
// mode 2: f32 token-major store.
// mode 3: softplus(v + bias[col]) -> bf16 TRANSPOSED store Cv[col][row] (ldc = transposed ld)
// mode 4: col<DTR -> bf16 token-major to Cv (ldc); col>=DTR -> bf16 transposed to Cv2 (ldc2)
// ---------------------------------------------------------------------------
__global__ __launch_bounds__(256)
void gemm_bt(const short* __restrict__ A, const short* __restrict__ Bt,
             void* __restrict__ Cv, void* __restrict__ Cv2, const float* __restrict__ bias,
             int N, int K, int lda, int ldb, int ldc, int ldc2, int mode)
{
  __shared__ short As[128][40];
  __shared__ short Bs[128][40];
  const int m0 = blockIdx.x * 128;
  const int n0 = blockIdx.y * 128;
  const int tid  = threadIdx.x;
  const int wave = tid >> 6, lane = tid & 63;
  const int wr = (wave >> 1) * 64, wc = (wave & 1) * 64;
  const int la = lane & 15, gq = lane >> 4;
  f32x4 acc[4][4] = {};

  for (int k0 = 0; k0 < K; k0 += 32) {
#pragma unroll
    for (int i = 0; i < 2; i++) {
      int idx = tid + i * 256;
      int row = idx >> 2, kc = (idx & 3) * 8;
      bf16x8 av = *(const bf16x8*)(A + (size_t)(m0 + row) * lda + k0 + kc);
      *(bf16x8*)(&As[row][kc]) = av;
      int bn = n0 + row;
      bf16x8 bv = {};
      if (bn < N) bv = *(const bf16x8*)(Bt + (size_t)bn * ldb + k0 + kc);
      *(bf16x8*)(&Bs[row][kc]) = bv;
    }
    __syncthreads();
    bf16x8 af[4], bfr[4];
#pragma unroll
    for (int i = 0; i < 4; i++) af[i]  = *(const bf16x8*)(&As[wr + i * 16 + la][gq * 8]);
#pragma unroll
    for (int j = 0; j < 4; j++) bfr[j] = *(const bf16x8*)(&Bs[wc + j * 16 + la][gq * 8]);
#pragma unroll
    for (int i = 0; i < 4; i++)
#pragma unroll
      for (int j = 0; j < 4; j++)
        acc[i][j] = __builtin_amdgcn_mfma_f32_16x16x32_bf16(af[i], bfr[j], acc[i][j], 0, 0, 0);
    __syncthreads();
  }

#pragma unroll
  for (int i = 0; i < 4; i++) {
    int rowb = m0 + wr + i * 16 + gq * 4;
#pragma unroll
    for (int j = 0; j < 4; j++) {
      int col = n0 + wc + j * 16 + la;
      if (col >= N) continue;
      if (mode == 2) {
#pragma unroll
        for (int r = 0; r < 4; r++)
          ((float*)Cv)[(size_t)(rowb + r) * ldc + col] = acc[i][j][r];
      } else if (mode == 3) {
        s16x4 pk;
#pragma unroll
        for (int r = 0; r < 4; r++) {
          float v = acc[i][j][r] + bias[col];
          v = (v > 20.f) ? v : log1pf(__expf(v));
          pk[r] = f2bs(v);
        }
        *(s16x4*)((short*)Cv + (size_t)col * ldc + rowb) = pk;
      } else if (mode == 4) {
        if (col < DTR) {
#pragma unroll
          for (int r = 0; r < 4; r++)
            ((short*)Cv)[(size_t)(rowb + r) * ldc + col] = f2bs(acc[i][j][r]);
        } else {
          s16x4 pk;
#pragma unroll
          for (int r = 0; r < 4; r++) pk[r] = f2bs(acc[i][j][r]);
          *(s16x4*)((short*)Cv2 + (size_t)(col - DTR) * ldc2 + rowb) = pk;
        }
      } else { // mode 0: plain bf16 token-major (legacy)
#pragma unroll
        for (int r = 0; r < 4; r++)
          ((short*)Cv)[(size_t)(rowb + r) * ldc + col] = f2bs(acc[i][j][r]);
      }
    }
  }
}

// ---------------------------------------------------------------------------
// f32-A MFMA GEMM for GEMM1.  Writes x-half (col<DI) token-major to X[.][DI],
// res-half (col>=DI) token-major to R[.][DI].  n0 tiles never straddle DI.
// ---------------------------------------------------------------------------
__global__ __launch_bounds__(256)
void gemm_a32_bt(const float* __restrict__ A, const short* __restrict__ Bt,
                 short* __restrict__ X, short* __restrict__ R,
                 int N, int K, int lda, int ldb)
{
  __shared__ short As[128][40];
  __shared__ short Bs[128][40];
  const int m0 = blockIdx.x * 128;
  const int n0 = blockIdx.y * 128;
  const int tid  = threadIdx.x;
  const int wave = tid >> 6, lane = tid & 63;
  const int wr = (wave >> 1) * 64, wc = (wave & 1) * 64;
  const int la = lane & 15, gq = lane >> 4;
  f32x4 acc[4][4] = {};

  for (int k0 = 0; k0 < K; k0 += 32) {
#pragma unroll
    for (int i = 0; i < 2; i++) {
      int idx = tid + i * 256;
      int row = idx >> 2, kc = (idx & 3) * 8;
      const float* ap = A + (size_t)(m0 + row) * lda + k0 + kc;
      float4 a0 = *(const float4*)ap;
      float4 a1 = *(const float4*)(ap + 4);
      union { bf16x8 v; short h[8]; } cv;
      cv.h[0] = f2bs(a0.x); cv.h[1] = f2bs(a0.y); cv.h[2] = f2bs(a0.z); cv.h[3] = f2bs(a0.w);
      cv.h[4] = f2bs(a1.x); cv.h[5] = f2bs(a1.y); cv.h[6] = f2bs(a1.z); cv.h[7] = f2bs(a1.w);
      *(bf16x8*)(&As[row][kc]) = cv.v;
      int bn = n0 + row;
      bf16x8 bv = {};
      if (bn < N) bv = *(const bf16x8*)(Bt + (size_t)bn * ldb + k0 + kc);
      *(bf16x8*)(&Bs[row][kc]) = bv;
    }
    __syncthreads();
    bf16x8 af[4], bfr[4];
#pragma unroll
    for (int i = 0; i < 4; i++) af[i]  = *(const bf16x8*)(&As[wr + i * 16 + la][gq * 8]);
#pragma unroll
    for (int j = 0; j < 4; j++) bfr[j] = *(const bf16x8*)(&Bs[wc + j * 16 + la][gq * 8]);
#pragma unroll
    for (int i = 0; i < 4; i++)
#pragma unroll
      for (int j = 0; j < 4; j++)
        acc[i][j] = __builtin_amdgcn_mfma_f32_16x16x32_bf16(af[i], bfr[j], acc[i][j], 0, 0, 0);
    __syncthreads();
  }

  short* base = (n0 < DI) ? X : R;
  const int cb = (n0 < DI) ? 0 : DI;
#pragma unroll
  for (int i = 0; i < 4; i++) {
    int rowb = m0 + wr + i * 16 + gq * 4;
#pragma unroll
    for (int j = 0; j < 4; j++) {
      int col = n0 + wc + j * 16 + la - cb;
#pragma unroll
      for (int r = 0; r < 4; r++)
        base[(size_t)(rowb + r) * DI + col] = f2bs(acc[i][j][r]);
    }
  }
}

// ---------------------------------------------------------------------------
// depthwise causal conv1d (k=4) + bias + SiLU.  Reads xb[token][DI].
// ---------------------------------------------------------------------------
__global__ __launch_bounds__(256)
void conv_silu(const short* __restrict__ xb, const float* __restrict__ cw,
               const float* __restrict__ cb, short* __restrict__ xs)
{
  const int token = blockIdx.x;
  const int l = token & (L_ - 1);
  const int d0 = threadIdx.x * 8;

  float w[32];
#pragma unroll
  for (int i = 0; i < 8; i++) {
    float4 t = *(const float4*)(cw + (size_t)(d0 + i) * 4);
    w[i * 4 + 0] = t.x; w[i * 4 + 1] = t.y; w[i * 4 + 2] = t.z; w[i * 4 + 3] = t.w;
  }
  float acc[8];
  {
    float4 b0 = *(const float4*)(cb + d0);
    float4 b1 = *(const float4*)(cb + d0 + 4);
    acc[0] = b0.x; acc[1] = b0.y; acc[2] = b0.z; acc[3] = b0.w;
    acc[4] = b1.x; acc[5] = b1.y; acc[6] = b1.z; acc[7] = b1.w;
  }
#pragma unroll
  for (int j = 0; j < 4; j++) {
    int lj = l - 3 + j;
    if (lj >= 0) {
      bf16x8 xv = *(const bf16x8*)(xb + (size_t)(token - 3 + j) * DI + d0);
#pragma unroll
      for (int i = 0; i < 8; i++) acc[i] += w[i * 4 + j] * bf2f(xv[i]);
    }
  }
  union { bf16x8 v; short h[8]; } o;
#pragma unroll
  for (int i = 0; i < 8; i++) {
    float v = acc[i];
    o.h[i] = f2bs(v * sigmoidf_fast(v));
  }
  *(bf16x8*)(xs + (size_t)token * DI + d0) = o.v;
}

// ---------------------------------------------------------------------------
// selective scan, 16 lanes per (b,d) channel (one per state n), fused gating.
// New structure:
//  - dt from dT[d][t]           (contiguous 32B / batch, broadcast in group)
//  - B,C from dbcT[n][t]        (contiguous 32B / batch / lane)
//  - u   from xs[t][d]          (16 scalar broadcast loads / batch)
//  - res from resy[t][d]        (1 per-lane scalar load; y overwrites in place)
//  - butterfly xor transpose-reduce: lane n ends with y(step l+n) -> full-wave
//    gate + single scatter store per batch.  u*D folded as u*D/16 per lane.
//  - 1-deep register double buffer (ping-pong) to hide load latency.
// ---------------------------------------------------------------------------
__global__ __launch_bounds__(256, 2)
void scan_kernel(const short* __restrict__ dT, const short* __restrict__ dbcT,
                 const short* __restrict__ xs, short* __restrict__ resy,
                 const float* __restrict__ A_log, const float* __restrict__ Dw,
                 const float* __restrict__ h0)
{
  const int lane = threadIdx.x & 63;
  const int grp = threadIdx.x >> 4, n = threadIdx.x & 15;
  const int ch = blockIdx.x * 16 + grp;          // ch = b*DI + d
  const int b = ch >> 11, d = ch & (DI - 1);
  const bool b3 = (lane & 8) != 0, b2 = (lane & 4) != 0,
             b1 = (lane & 2) != 0, b0 = (lane & 1) != 0;
  const float An = -__expf(A_log[d * NST + n]);
  const float Dd16 = Dw[d] * 0.0625f;            // D/16: summed 16x in reduce
  float h = h0[(size_t)ch * NST + n];

  const size_t t0 = (size_t)b * L_;
  const short* dRow = dT   + (size_t)d * NTOK + t0;
  const short* bRow = dbcT + (size_t)n * NTOK + t0;
  const short* cRow = bRow + (size_t)NST * NTOK;
  const short* uCol = xs   + t0 * DI + d;
  short*       yCol = resy + (t0 + n) * DI + d;  // res read / y write, per-lane row

  auto LOADB = [&](int lv, bf16x8& t0v, bf16x8& t1v, bf16x8& B0v, bf16x8& B1v,
                   bf16x8& C0v, bf16x8& C1v, short* ur, short& rr) {
    t0v = *(const bf16x8*)(dRow + lv);
    t1v = *(const bf16x8*)(dRow + lv + 8);
    B0v = *(const bf16x8*)(bRow + lv);
    B1v = *(const bf16x8*)(bRow + lv + 8);
    C0v = *(const bf16x8*)(cRow + lv);
    C1v = *(const bf16x8*)(cRow + lv + 8);
#pragma unroll
    for (int s = 0; s < 16; s++) ur[s] = uCol[(size_t)(lv + s) * DI];
    rr = yCol[(size_t)lv * DI];
  };

  auto STEP = [&](int lv, bf16x8 t0v, bf16x8 t1v, bf16x8 B0v, bf16x8 B1v,
                  bf16x8 C0v, bf16x8 C1v, const short* ur, short rr) {
    // ---- precompute (independent of h) ----
    float dA[16], w[16], g[16];
#pragma unroll
    for (int s = 0; s < 16; s++) {
      float dt = bf2f(s < 8 ? t0v[s] : t1v[s - 8]);
      float uu = bf2f(ur[s]);
      dA[s] = __expf(dt * An);
      g[s]  = uu * Dd16;
      w[s]  = dt * uu * bf2f(s < 8 ? B0v[s] : B1v[s - 8]);
    }
    // ---- serial chain (16 FMAs) + per-state output term ----
    float p[16];
#pragma unroll
    for (int s = 0; s < 16; s++) {
      h = __builtin_fmaf(dA[s], h, w[s]);
      p[s] = __builtin_fmaf(h, bf2f(s < 8 ? C0v[s] : C1v[s - 8]), g[s]);
    }
    // ---- butterfly transpose-reduce: lane n -> sum over states of p[n] ----
    float q8[8];
#pragma unroll
    for (int i = 0; i < 8; i++) {
      float keep = b3 ? p[i + 8] : p[i];
      float send = b3 ? p[i]     : p[i + 8];
      q8[i] = keep + swz_xor8(send);
    }
    float q4[4];
#pragma unroll
    for (int i = 0; i < 4; i++) {
      float keep = b2 ? q8[i + 4] : q8[i];
      float send = b2 ? q8[i]     : q8[i + 4];
      q4[i] = keep + swz_xor4(send);
    }
    float q2[2];
#pragma unroll
    for (int i = 0; i < 2; i++) {
      float keep = b1 ? q4[i + 2] : q4[i];
      float send = b1 ? q4[i]     : q4[i + 2];
      q2[i] = keep + qperm<0x4E>(send);       // quad_perm [2,3,0,1] = xor 2
    }
    float keep = b0 ? q2[1] : q2[0];
    float send = b0 ? q2[0] : q2[1];
    float ysum = keep + qperm<0xB1>(send);     // quad_perm [1,0,3,2] = xor 1
    // ---- full-wave gate + scatter store (lane n owns step lv+n) ----
    float r = bf2f(rr);
    float yv = ysum * (r * sigmoidf_fast(r));
    yCol[(size_t)lv * DI] = f2bs(yv);
  };

  bf16x8 a0, a1, a2, a3, a4, a5; short ua[16]; short ra;
  bf16x8 c0, c1, c2, c3, c4, c5; short ub[16]; short rb;
  LOADB(0, a0, a1, a2, a3, a4, a5, ua, ra);
  for (int l = 0; l < L_; l += 32) {
    LOADB(l + 16, c0, c1, c2, c3, c4, c5, ub, rb);
    STEP(l, a0, a1, a2, a3, a4, a5, ua, ra);
    if (l + 32 < L_) LOADB(l + 32, a0, a1, a2, a3, a4, a5, ua, ra);
    STEP(l + 16, c0, c1, c2, c3, c4, c5, ub, rb);
  }
}

// ---------------------------------------------------------------------------
extern "C" void kernel_launch(void* const* d_in, const int* in_sizes, int n_in,
                              void* d_out, int out_size, void* d_ws, size_t ws_size,
                              hipStream_t stream)
{
  const float* u        = (const float*)d_in[0];
  const float* hiddens  = (const float*)d_in[1];
  const float* in_proj  = (const float*)d_in[2];
  const float* conv_w   = (const float*)d_in[3];
  const float* conv_b   = (const float*)d_in[4];
  const float* x_proj   = (const float*)d_in[5];   // (2048, 96)
  const float* dt_proj  = (const float*)d_in[6];   // (64, 2048)
  const float* dt_bias  = (const float*)d_in[7];
  const float* A_log    = (const float*)d_in[8];
  const float* Dw       = (const float*)d_in[9];
  const float* out_proj = (const float*)d_in[10];
  float* out = (float*)d_out;

  // workspace: ~74 MiB (under the previously proven 78 MiB)
  char* w = (char*)d_ws;
  short* Wt1  = (short*)w;                                 // in_proj^T (4096x1024), 8 MiB
  short* Wt4  = Wt1;                                       // out_proj^T reuses Wt1 after GEMM1
  w += (size_t)4096 * 1024 * 2;
  short* Wxp  = (short*)w; w += (size_t)96   * 2048 * 2;   // x_proj^T   (96 x 2048)
  short* dtw  = (short*)w; w += (size_t)2048 * 64   * 2;   // dt_proj^T  (2048 x 64)
  short* xbuf = (short*)w; w += (size_t)NTOK * DI   * 2;   // x (token-major) -> dT (chan-major)
  short* resy = (short*)w; w += (size_t)NTOK * DI   * 2;   // res (token-major) -> y in-place
  short* dbc  = (short*)w; w += (size_t)NTOK * DTR  * 2;   // dt_rank part, token-major (8192x64)
  short* dbcT = (short*)w; w += (size_t)32   * NTOK * 2;   // B|C transposed (32 x 8192)
  short* xs   = (short*)d_out;                             // conv out borrows d_out
  short* dT   = xbuf;                                      // delta^T overlays dead x

  dim3 tb(32, 8);
  transpose_f2b<<<dim3(32, 128), tb, 0, stream>>>(in_proj,  Wt1, 1024, 4096, 4096, 1024);
  transpose_f2b<<<dim3(64, 3),   tb, 0, stream>>>(x_proj,   Wxp, 2048, 96,   96,   2048);
  transpose_f2b<<<dim3(2, 64),   tb, 0, stream>>>(dt_proj,  dtw, 64,   2048, 2048, 64);

  // GEMM1: [x | res] = u @ in_proj, split into xbuf / resy (both token-major, ld=DI)
  gemm_a32_bt<<<dim3(64, 32), 256, 0, stream>>>(u, Wt1, xbuf, resy, 4096, 1024, 1024, 1024);
  // out_proj^T into the now-free Wt1 region (stream-ordered after GEMM1)
  transpose_f2b<<<dim3(64, 32),  tb, 0, stream>>>(out_proj, Wt4, 2048, 1024, 1024, 2048);
  // conv + silu -> xs (token-major, in d_out)
  conv_silu<<<NTOK, 256, 0, stream>>>(xbuf, conv_w, conv_b, xs);
  // GEMM2: dbc = xs @ x_proj; dt-rank cols token-major, B/C cols transposed to dbcT
  gemm_bt<<<dim3(64, 1), 256, 0, stream>>>(xs, Wxp, dbc, dbcT, nullptr,
                                           96, 2048, 2048, 2048, DTR, NTOK, 4);
  // GEMM3: delta = softplus(dbc @ dt_proj + bias) -> TRANSPOSED dT[d][t] (overlays xbuf)
  gemm_bt<<<dim3(64, 16), 256, 0, stream>>>(dbc, dtw, dT, nullptr, dt_bias,
                                            2048, 64, DTR, 64, NTOK, 0, 3);
  // selective scan + gated epilogue: y overwrites res in-place (token-major)
  scan_kernel<<<512, 256, 0, stream>>>(dT, dbcT, xs, resy, A_log, Dw, hiddens);
  // GEMM4: out = y @ out_proj  (8192 x 1024, f32 store)
  gemm_bt<<<dim3(64, 8), 256, 0, stream>>>(resy, Wt4, out, nullptr, nullptr,
                                           1024, 2048, 2048, 2048, 1024, 0, 2);
}

// Round 2
// 767.912 us; speedup vs baseline: 1.2696x; 1.0390x over previous
//
#include <hip/hip_runtime.h>
#include <hip/hip_bf16.h>
#include <cstddef>

#define B_   4
#define L_   2048
#define DM   1024
#define DI   2048
#define NST  16
#define DTR  64        // (1024+15)//16 = 64
#define NBC  96        // DTR + 2*NST
#define NTOK 8192      // B_*L_

using bf16 = __hip_bfloat16;
typedef __attribute__((ext_vector_type(8))) short bf16x8;
typedef __attribute__((ext_vector_type(4))) short s16x4;
typedef __attribute__((ext_vector_type(4))) float f32x4;

__device__ __forceinline__ float bf2f(short s) {
  unsigned u = ((unsigned)(unsigned short)s) << 16;
  float f; __builtin_memcpy(&f, &u, 4); return f;
}
__device__ __forceinline__ short f2bs(float f) {
  __hip_bfloat16 h = __float2bfloat16(f);
  short s; __builtin_memcpy(&s, &h, 2); return s;
}
__device__ __forceinline__ float sigmoidf_fast(float x) {
  return 1.f / (1.f + __expf(-x));
}

// async global->LDS, 16B per lane (dest must be wave-uniform base + lane*16)
#define GLD16(g, l) __builtin_amdgcn_global_load_lds( \
  (const __attribute__((address_space(1))) unsigned int*)(g), \
  (__attribute__((address_space(3))) unsigned int*)(l), 16, 0, 0)

// cross-lane xor shuffles for the 16-state butterfly reduce
__device__ __forceinline__ float swz_xor8(float x) {
  return __builtin_bit_cast(float,
    __builtin_amdgcn_ds_swizzle(__builtin_bit_cast(int, x), 0x201F)); // lane ^= 8
}
__device__ __forceinline__ float swz_xor4(float x) {
  return __builtin_bit_cast(float,
    __builtin_amdgcn_ds_swizzle(__builtin_bit_cast(int, x), 0x101F)); // lane ^= 4
}
template<int CTRL>
__device__ __forceinline__ float qperm(float x) {  // DPP quad_perm, full VALU rate
  return __builtin_bit_cast(float,
    __builtin_amdgcn_update_dpp(0, __builtin_bit_cast(int, x), CTRL, 0xf, 0xf, false));
}

// ---------------------------------------------------------------------------
// f32 -> bf16 bulk convert (n elements = grid*256*8 exactly)
// ---------------------------------------------------------------------------
__global__ __launch_bounds__(256)
void cvt_f2b(const float* __restrict__ in, short* __restrict__ out)
{
  const size_t i = ((size_t)blockIdx.x * 256 + threadIdx.x) * 8;
  float4 a0 = *(const float4*)(in + i);
  float4 a1 = *(const float4*)(in + i + 4);
  union { bf16x8 v; short h[8]; } o;
  o.h[0] = f2bs(a0.x); o.h[1] = f2bs(a0.y); o.h[2] = f2bs(a0.z); o.h[3] = f2bs(a0.w);
  o.h[4] = f2bs(a1.x); o.h[5] = f2bs(a1.y); o.h[6] = f2bs(a1.z); o.h[7] = f2bs(a1.w);
  *(bf16x8*)(out + i) = o.v;
}

// ---------------------------------------------------------------------------
// transpose f32 in -> bf16 out, zero-pad: out[c][r] = (r<R&&c<Cc) ? in[r*lin+c] : 0
// ---------------------------------------------------------------------------
__global__ __launch_bounds__(256)
void transpose_f2b(const float* __restrict__ in, short* __restrict__ out,
                   int R, int Cc, int lin, int lout)
{
  __shared__ short t[32][33];
  const int r0 = blockIdx.x * 32, c0 = blockIdx.y * 32;
  const int tx = threadIdx.x, ty = threadIdx.y;
#pragma unroll
  for (int i = 0; i < 4; i++) {
    int r = r0 + ty + i * 8;
    int c = c0 + tx;
    short v = 0;
    if (r < R && c < Cc) v = f2bs(in[(size_t)r * lin + c]);
    t[ty + i * 8][tx] = v;
  }
  __syncthreads();
#pragma unroll
  for (int i = 0; i < 4; i++) {
    int c = c0 + ty + i * 8;
    int r = r0 + tx;
    if (c < Cc && r < lout) out[(size_t)c * lout + r] = t[tx][ty + i * 8];
  }
}

// ---------------------------------------------------------------------------
// bf16 MFMA GEMM, C[M x N] = A[M x K] * Bt[N x K]^T.  128x128 tile, BK=32,
// 4 waves each 64x64 (4x4 of 16x16x32 MFMA).  global_load_lds (16B) staging,
// linear LDS tiles (m97 structure).  B-tile rows are read UNGUARDED: the Bt
// buffer must be allocated (and is) with >= ceil128(N) rows.
// mode 2: f32 token-major store.
// mode 3: softplus(v + bias[col]) -> bf16 TRANSPOSED store Cv[col][row] (ldc transposed ld)
// mode 4: col<DTR -> bf16 token-major to Cv (ldc); col>=DTR -> bf16 transposed to Cv2 (ldc2)
// mode 5: col<DI  -> bf16 token-major to Cv (ldc); col>=DI  -> token-major to Cv2 (ldc2)
// ---------------------------------------------------------------------------
__global__ __launch_bounds__(256)
void gemm_bt(const short* __restrict__ A, const short* __restrict__ Bt,
             void* __restrict__ Cv, void* __restrict__ Cv2, const float* __restrict__ bias,
             int N, int K, int lda, int ldb, int ldc, int ldc2, int mode)
{
  __shared__ short As[128][32];
  __shared__ short Bs[128][32];
  const int m0 = blockIdx.x * 128;
  const int n0 = blockIdx.y * 128;
  const int tid  = threadIdx.x;
  const int wave = tid >> 6, lane = tid & 63;
  const int wr = (wave >> 1) * 64, wc = (wave & 1) * 64;
  const int la = lane & 15, gq = lane >> 4;
  f32x4 acc[4][4] = {};

  for (int k0 = 0; k0 < K; k0 += 32) {
#pragma unroll
    for (int i = 0; i < 2; i++) {
      int idx = tid + i * 256;
      int row = idx >> 2, kc = (idx & 3) * 8;
      GLD16(A  + (size_t)(m0 + row) * lda + k0 + kc, &As[row][kc]);
      GLD16(Bt + (size_t)(n0 + row) * ldb + k0 + kc, &Bs[row][kc]);
    }
    __syncthreads();
    bf16x8 af[4], bfr[4];
#pragma unroll
    for (int i = 0; i < 4; i++) af[i]  = *(const bf16x8*)(&As[wr + i * 16 + la][gq * 8]);
#pragma unroll
    for (int j = 0; j < 4; j++) bfr[j] = *(const bf16x8*)(&Bs[wc + j * 16 + la][gq * 8]);
#pragma unroll
    for (int i = 0; i < 4; i++)
#pragma unroll
      for (int j = 0; j < 4; j++)
        acc[i][j] = __builtin_amdgcn_mfma_f32_16x16x32_bf16(af[i], bfr[j], acc[i][j], 0, 0, 0);
    __syncthreads();
  }

#pragma unroll
  for (int i = 0; i < 4; i++) {
    int rowb = m0 + wr + i * 16 + gq * 4;
#pragma unroll
    for (int j = 0; j < 4; j++) {
      int col = n0 + wc + j * 16 + la;
      if (col >= N) continue;
      if (mode == 2) {
#pragma unroll
        for (int r = 0; r < 4; r++)
          ((float*)Cv)[(size_t)(rowb + r) * ldc + col] = acc[i][j][r];
      } else if (mode == 3) {
        s16x4 pk;
#pragma unroll
        for (int r = 0; r < 4; r++) {
          float v = acc[i][j][r] + bias[col];
          v = (v > 20.f) ? v : log1pf(__expf(v));
          pk[r] = f2bs(v);
        }
        *(s16x4*)((short*)Cv + (size_t)col * ldc + rowb) = pk;
      } else if (mode == 4) {
        if (col < DTR) {
#pragma unroll
          for (int r = 0; r < 4; r++)
            ((short*)Cv)[(size_t)(rowb + r) * ldc + col] = f2bs(acc[i][j][r]);
        } else {
          s16x4 pk;
#pragma unroll
          for (int r = 0; r < 4; r++) pk[r] = f2bs(acc[i][j][r]);
          *(s16x4*)((short*)Cv2 + (size_t)(col - DTR) * ldc2 + rowb) = pk;
        }
      } else if (mode == 5) {
        short* base = (col < DI) ? (short*)Cv : (short*)Cv2;
        int c = (col < DI) ? col : col - DI;
        int ld = (col < DI) ? ldc : ldc2;
#pragma unroll
        for (int r = 0; r < 4; r++)
          base[(size_t)(rowb + r) * ld + c] = f2bs(acc[i][j][r]);
      } else { // mode 0: plain bf16 token-major
#pragma unroll
        for (int r = 0; r < 4; r++)
          ((short*)Cv)[(size_t)(rowb + r) * ldc + col] = f2bs(acc[i][j][r]);
      }
    }
  }
}

// ---------------------------------------------------------------------------
// depthwise causal conv1d (k=4) + bias + SiLU.  Reads xb[token][DI].
// ---------------------------------------------------------------------------
__global__ __launch_bounds__(256)
void conv_silu(const short* __restrict__ xb, const float* __restrict__ cw,
               const float* __restrict__ cb, short* __restrict__ xs)
{
  const int token = blockIdx.x;
  const int l = token & (L_ - 1);
  const int d0 = threadIdx.x * 8;

  float w[32];
#pragma unroll
  for (int i = 0; i < 8; i++) {
    float4 t = *(const float4*)(cw + (size_t)(d0 + i) * 4);
    w[i * 4 + 0] = t.x; w[i * 4 + 1] = t.y; w[i * 4 + 2] = t.z; w[i * 4 + 3] = t.w;
  }
  float acc[8];
  {
    float4 b0 = *(const float4*)(cb + d0);
    float4 b1 = *(const float4*)(cb + d0 + 4);
    acc[0] = b0.x; acc[1] = b0.y; acc[2] = b0.z; acc[3] = b0.w;
    acc[4] = b1.x; acc[5] = b1.y; acc[6] = b1.z; acc[7] = b1.w;
  }
#pragma unroll
  for (int j = 0; j < 4; j++) {
    int lj = l - 3 + j;
    if (lj >= 0) {
      bf16x8 xv = *(const bf16x8*)(xb + (size_t)(token - 3 + j) * DI + d0);
#pragma unroll
      for (int i = 0; i < 8; i++) acc[i] += w[i * 4 + j] * bf2f(xv[i]);
    }
  }
  union { bf16x8 v; short h[8]; } o;
#pragma unroll
  for (int i = 0; i < 8; i++) {
    float v = acc[i];
    o.h[i] = f2bs(v * sigmoidf_fast(v));
  }
  *(bf16x8*)(xs + (size_t)token * DI + d0) = o.v;
}

// ---------------------------------------------------------------------------
// selective scan, 16 lanes per (b,d) channel (one per state n), fused gating.
//  - dt from dT[d][t], B/C from dbcT[n][t] (contiguous 32B vec loads)
//  - u from xs[t][d] (scalar broadcast), res from resy[t][d] (per-lane)
//  - butterfly xor transpose-reduce: lane n ends with y(step l+n) -> full-wave
//    gate + scatter store.  u*D folded as u*D/16 per lane.
//  - 1-deep register double buffer (ping-pong) to hide load latency.
// ---------------------------------------------------------------------------
__global__ __launch_bounds__(256, 2)
void scan_kernel(const short* __restrict__ dT, const short* __restrict__ dbcT,
                 const short* __restrict__ xs, short* __restrict__ resy,
                 const float* __restrict__ A_log, const float* __restrict__ Dw,
                 const float* __restrict__ h0)
{
  const int lane = threadIdx.x & 63;
  const int grp = threadIdx.x >> 4, n = threadIdx.x & 15;
  const int ch = blockIdx.x * 16 + grp;          // ch = b*DI + d
  const int b = ch >> 11, d = ch & (DI - 1);
  const bool b3 = (lane & 8) != 0, b2 = (lane & 4) != 0,
             b1 = (lane & 2) != 0, b0 = (lane & 1) != 0;
  const float An = -__expf(A_log[d * NST + n]);
  const float Dd16 = Dw[d] * 0.0625f;            // D/16: summed 16x in reduce
  float h = h0[(size_t)ch * NST + n];

  const size_t t0 = (size_t)b * L_;
  const short* dRow = dT   + (size_t)d * NTOK + t0;
  const short* bRow = dbcT + (size_t)n * NTOK + t0;
  const short* cRow = bRow + (size_t)NST * NTOK;
  const short* uCol = xs   + t0 * DI + d;
  short*       yCol = resy + (t0 + n) * DI + d;  // res read / y write, per-lane row

  auto LOADB = [&](int lv, bf16x8& t0v, bf16x8& t1v, bf16x8& B0v, bf16x8& B1v,
                   bf16x8& C0v, bf16x8& C1v, short* ur, short& rr) {
    t0v = *(const bf16x8*)(dRow + lv);
    t1v = *(const bf16x8*)(dRow + lv + 8);
    B0v = *(const bf16x8*)(bRow + lv);
    B1v = *(const bf16x8*)(bRow + lv + 8);
    C0v = *(const bf16x8*)(cRow + lv);
    C1v = *(const bf16x8*)(cRow + lv + 8);
#pragma unroll
    for (int s = 0; s < 16; s++) ur[s] = uCol[(size_t)(lv + s) * DI];
    rr = yCol[(size_t)lv * DI];
  };

  auto STEP = [&](int lv, bf16x8 t0v, bf16x8 t1v, bf16x8 B0v, bf16x8 B1v,
                  bf16x8 C0v, bf16x8 C1v, const short* ur, short rr) {
    // ---- precompute (independent of h) ----
    float dA[16], w[16], g[16];
#pragma unroll
    for (int s = 0; s < 16; s++) {
      float dt = bf2f(s < 8 ? t0v[s] : t1v[s - 8]);
      float uu = bf2f(ur[s]);
      dA[s] = __expf(dt * An);
      g[s]  = uu * Dd16;
      w[s]  = dt * uu * bf2f(s < 8 ? B0v[s] : B1v[s - 8]);
    }
    // ---- serial chain (16 FMAs) + per-state output term ----
    float p[16];
#pragma unroll
    for (int s = 0; s < 16; s++) {
      h = __builtin_fmaf(dA[s], h, w[s]);
      p[s] = __builtin_fmaf(h, bf2f(s < 8 ? C0v[s] : C1v[s - 8]), g[s]);
    }
    // ---- butterfly transpose-reduce: lane n -> sum over states of p[n] ----
    float q8[8];
#pragma unroll
    for (int i = 0; i < 8; i++) {
      float keep = b3 ? p[i + 8] : p[i];
      float send = b3 ? p[i]     : p[i + 8];
      q8[i] = keep + swz_xor8(send);
    }
    float q4[4];
#pragma unroll
    for (int i = 0; i < 4; i++) {
      float keep = b2 ? q8[i + 4] : q8[i];
      float send = b2 ? q8[i]     : q8[i + 4];
      q4[i] = keep + swz_xor4(send);
    }
    float q2[2];
#pragma unroll
    for (int i = 0; i < 2; i++) {
      float keep = b1 ? q4[i + 2] : q4[i];
      float send = b1 ? q4[i]     : q4[i + 2];
      q2[i] = keep + qperm<0x4E>(send);       // quad_perm [2,3,0,1] = xor 2
    }
    float keep = b0 ? q2[1] : q2[0];
    float send = b0 ? q2[0] : q2[1];
    float ysum = keep + qperm<0xB1>(send);     // quad_perm [1,0,3,2] = xor 1
    // ---- full-wave gate + scatter store (lane n owns step lv+n) ----
    float r = bf2f(rr);
    float yv = ysum * (r * sigmoidf_fast(r));
    yCol[(size_t)lv * DI] = f2bs(yv);
  };

  bf16x8 a0, a1, a2, a3, a4, a5; short ua[16]; short ra;
  bf16x8 c0, c1, c2, c3, c4, c5; short ub[16]; short rb;
  LOADB(0, a0, a1, a2, a3, a4, a5, ua, ra);
  for (int l = 0; l < L_; l += 32) {
    LOADB(l + 16, c0, c1, c2, c3, c4, c5, ub, rb);
    STEP(l, a0, a1, a2, a3, a4, a5, ua, ra);
    if (l + 32 < L_) LOADB(l + 32, a0, a1, a2, a3, a4, a5, ua, ra);
    STEP(l + 16, c0, c1, c2, c3, c4, c5, ub, rb);
  }
}

// ---------------------------------------------------------------------------
extern "C" void kernel_launch(void* const* d_in, const int* in_sizes, int n_in,
                              void* d_out, int out_size, void* d_ws, size_t ws_size,
                              hipStream_t stream)
{
  const float* u        = (const float*)d_in[0];
  const float* hiddens  = (const float*)d_in[1];
  const float* in_proj  = (const float*)d_in[2];
  const float* conv_w   = (const float*)d_in[3];
  const float* conv_b   = (const float*)d_in[4];
  const float* x_proj   = (const float*)d_in[5];   // (2048, 96)
  const float* dt_proj  = (const float*)d_in[6];   // (64, 2048)
  const float* dt_bias  = (const float*)d_in[7];
  const float* A_log    = (const float*)d_in[8];
  const float* Dw       = (const float*)d_in[9];
  const float* out_proj = (const float*)d_in[10];
  float* out = (float*)d_out;

  // workspace: ~74 MiB (under the previously proven 78 MiB)
  char* w = (char*)d_ws;
  short* Wt1  = (short*)w;                                 // in_proj^T (4096x1024), 8 MiB
  short* Wt4  = Wt1;                                       // out_proj^T reuses Wt1 after GEMM1
  w += (size_t)4096 * 1024 * 2;
  short* Wxp  = (short*)w; w += (size_t)128  * 2048 * 2;   // x_proj^T, padded to 128 rows
  short* dtw  = (short*)w; w += (size_t)2048 * 64   * 2;   // dt_proj^T  (2048 x 64)
  short* xbuf = (short*)w; w += (size_t)NTOK * DI   * 2;   // x (token-major) -> dT (chan-major)
  short* resy = (short*)w; w += (size_t)NTOK * DI   * 2;   // res (token-major) -> y in-place
  short* dbc  = (short*)w; w += (size_t)NTOK * DTR  * 2;   // dt_rank part, token-major (8192x64)
  short* dbcT = (short*)w; w += (size_t)32   * NTOK * 2;   // B|C transposed (32 x 8192)
  short* ub   = (short*)d_out;                             // u in bf16 (16 MiB, dead after GEMM1)
  short* xs   = (short*)d_out;                             // conv out borrows d_out after GEMM1
  short* dT   = xbuf;                                      // delta^T overlays dead x

  dim3 tb(32, 8);
  cvt_f2b<<<4096, 256, 0, stream>>>(u, ub);                // u -> bf16 (8192x1024)
  transpose_f2b<<<dim3(32, 128), tb, 0, stream>>>(in_proj,  Wt1, 1024, 4096, 4096, 1024);
  transpose_f2b<<<dim3(64, 3),   tb, 0, stream>>>(x_proj,   Wxp, 2048, 96,   96,   2048);
  transpose_f2b<<<dim3(2, 64),   tb, 0, stream>>>(dt_proj,  dtw, 64,   2048, 2048, 64);

  // GEMM1: [x | res] = ub @ in_proj, split into xbuf / resy (token-major, ld=DI)
  gemm_bt<<<dim3(64, 32), 256, 0, stream>>>(ub, Wt1, xbuf, resy, nullptr,
                                            4096, 1024, 1024, 1024, DI, DI, 5);
  // out_proj^T into the now-free Wt1 region (stream-ordered after GEMM1)
  transpose_f2b<<<dim3(64, 32),  tb, 0, stream>>>(out_proj, Wt4, 2048, 1024, 1024, 2048);
  // conv + silu -> xs (token-major, in d_out; ub dead from here)
  conv_silu<<<NTOK, 256, 0, stream>>>(xbuf, conv_w, conv_b, xs);
  // GEMM2: dbc = xs @ x_proj; dt-rank cols token-major, B/C cols transposed to dbcT
  gemm_bt<<<dim3(64, 1), 256, 0, stream>>>(xs, Wxp, dbc, dbcT, nullptr,
                                           96, 2048, 2048, 2048, DTR, NTOK, 4);
  // GEMM3: delta = softplus(dbc @ dt_proj + bias) -> TRANSPOSED dT[d][t] (overlays xbuf)
  gemm_bt<<<dim3(64, 16), 256, 0, stream>>>(dbc, dtw, dT, nullptr, dt_bias,
                                            2048, 64, DTR, 64, NTOK, 0, 3);
  // selective scan + gated epilogue: y overwrites res in-place (token-major)
  scan_kernel<<<512, 256, 0, stream>>>(dT, dbcT, xs, resy, A_log, Dw, hiddens);
  // GEMM4: out = y @ out_proj  (8192 x 1024, f32 store)
  gemm_bt<<<dim3(64, 8), 256, 0, stream>>>(resy, Wt4, out, nullptr, nullptr,
                                           1024, 2048, 2048, 2048, 1024, 0, 2);
}

// Round 3
// 734.696 us; speedup vs baseline: 1.3270x; 1.0452x over previous
//
#include <hip/hip_runtime.h>
#include <hip/hip_bf16.h>
#include <cstddef>

#define B_   4
#define L_   2048
#define DM   1024
#define DI   2048
#define NST  16
#define DTR  64        // (1024+15)//16 = 64
#define NBC  96        // DTR + 2*NST
#define NTOK 8192      // B_*L_

using bf16 = __hip_bfloat16;
typedef __attribute__((ext_vector_type(8))) short bf16x8;
typedef __attribute__((ext_vector_type(4))) short s16x4;
typedef __attribute__((ext_vector_type(4))) float f32x4;

__device__ __forceinline__ float bf2f(short s) {
  unsigned u = ((unsigned)(unsigned short)s) << 16;
  float f; __builtin_memcpy(&f, &u, 4); return f;
}
__device__ __forceinline__ short f2bs(float f) {
  __hip_bfloat16 h = __float2bfloat16(f);
  short s; __builtin_memcpy(&s, &h, 2); return s;
}
__device__ __forceinline__ float sigmoidf_fast(float x) {
  return 1.f / (1.f + __expf(-x));
}

// async global->LDS, 16B per lane (dest must be wave-uniform base + lane*16)
#define GLD16(g, l) __builtin_amdgcn_global_load_lds( \
  (const __attribute__((address_space(1))) unsigned int*)(g), \
  (__attribute__((address_space(3))) unsigned int*)(l), 16, 0, 0)

// cross-lane xor shuffles for the 16-state butterfly reduce
__device__ __forceinline__ float swz_xor8(float x) {
  return __builtin_bit_cast(float,
    __builtin_amdgcn_ds_swizzle(__builtin_bit_cast(int, x), 0x201F)); // lane ^= 8
}
__device__ __forceinline__ float swz_xor4(float x) {
  return __builtin_bit_cast(float,
    __builtin_amdgcn_ds_swizzle(__builtin_bit_cast(int, x), 0x101F)); // lane ^= 4
}
template<int CTRL>
__device__ __forceinline__ float qperm(float x) {  // DPP quad_perm, full VALU rate
  return __builtin_bit_cast(float,
    __builtin_amdgcn_update_dpp(0, __builtin_bit_cast(int, x), CTRL, 0xf, 0xf, false));
}

// ---------------------------------------------------------------------------
// f32 -> bf16 bulk convert (n elements = grid*256*8 exactly)
// ---------------------------------------------------------------------------
__global__ __launch_bounds__(256)
void cvt_f2b(const float* __restrict__ in, short* __restrict__ out)
{
  const size_t i = ((size_t)blockIdx.x * 256 + threadIdx.x) * 8;
  float4 a0 = *(const float4*)(in + i);
  float4 a1 = *(const float4*)(in + i + 4);
  union { bf16x8 v; short h[8]; } o;
  o.h[0] = f2bs(a0.x); o.h[1] = f2bs(a0.y); o.h[2] = f2bs(a0.z); o.h[3] = f2bs(a0.w);
  o.h[4] = f2bs(a1.x); o.h[5] = f2bs(a1.y); o.h[6] = f2bs(a1.z); o.h[7] = f2bs(a1.w);
  *(bf16x8*)(out + i) = o.v;
}

// ---------------------------------------------------------------------------
// transpose f32 in -> bf16 out, zero-pad: out[c][r] = (r<R&&c<Cc) ? in[r*lin+c] : 0
// ---------------------------------------------------------------------------
__global__ __launch_bounds__(256)
void transpose_f2b(const float* __restrict__ in, short* __restrict__ out,
                   int R, int Cc, int lin, int lout)
{
  __shared__ short t[32][33];
  const int r0 = blockIdx.x * 32, c0 = blockIdx.y * 32;
  const int tx = threadIdx.x, ty = threadIdx.y;
#pragma unroll
  for (int i = 0; i < 4; i++) {
    int r = r0 + ty + i * 8;
    int c = c0 + tx;
    short v = 0;
    if (r < R && c < Cc) v = f2bs(in[(size_t)r * lin + c]);
    t[ty + i * 8][tx] = v;
  }
  __syncthreads();
#pragma unroll
  for (int i = 0; i < 4; i++) {
    int c = c0 + ty + i * 8;
    int r = r0 + tx;
    if (c < Cc && r < lout) out[(size_t)c * lout + r] = t[tx][ty + i * 8];
  }
}

// ---------------------------------------------------------------------------
// bf16 MFMA GEMM, C[M x N] = A[M x K] * Bt[N x K]^T.  128x128 tile, BK=32,
// 4 waves each 64x64 (4x4 of 16x16x32 MFMA).  global_load_lds (16B) staging,
// linear LDS tiles (m97 structure).  A/B tile rows are read UNGUARDED: both
// buffers must be allocated with >= ceil128 rows (they are).
// XCD-aware bijective block swizzle (requires gridDim.x*gridDim.y % 8 == 0):
// each XCD gets a contiguous chunk of m-major work -> B-panels L2-resident.
// mode 2: f32 token-major store.
// mode 3: softplus(v + bias[col]) -> bf16 TRANSPOSED scatter (legacy, unused)
// mode 4: col<DTR -> bf16 token-major to Cv (ldc); col>=DTR -> bf16 transposed to Cv2 (ldc2)
// mode 5: col<DI  -> bf16 token-major to Cv (ldc); col>=DI  -> token-major to Cv2 (ldc2)
// mode 6: softplus(v + bias[ROW]) -> bf16 row-major store (ldc)  [GEMM3 swapped form]
// ---------------------------------------------------------------------------
__global__ __launch_bounds__(256)
void gemm_bt(const short* __restrict__ A, const short* __restrict__ Bt,
             void* __restrict__ Cv, void* __restrict__ Cv2, const float* __restrict__ bias,
             int N, int K, int lda, int ldb, int ldc, int ldc2, int mode)
{
  __shared__ short As[128][32];
  __shared__ short Bs[128][32];
  // ---- XCD swizzle: dispatch i -> XCD i%8; give XCD k contiguous work chunk ----
  const int gx = gridDim.x;
  const int nwg = gx * gridDim.y;
  const int lid = blockIdx.x + gx * blockIdx.y;
  const int cpx = nwg >> 3;                       // nwg % 8 == 0 for all call sites
  const int swz = (lid & 7) * cpx + (lid >> 3);
  const int m0 = (swz % gx) * 128;
  const int n0 = (swz / gx) * 128;
  const int tid  = threadIdx.x;
  const int wave = tid >> 6, lane = tid & 63;
  const int wr = (wave >> 1) * 64, wc = (wave & 1) * 64;
  const int la = lane & 15, gq = lane >> 4;
  f32x4 acc[4][4] = {};

  for (int k0 = 0; k0 < K; k0 += 32) {
#pragma unroll
    for (int i = 0; i < 2; i++) {
      int idx = tid + i * 256;
      int row = idx >> 2, kc = (idx & 3) * 8;
      GLD16(A  + (size_t)(m0 + row) * lda + k0 + kc, &As[row][kc]);
      GLD16(Bt + (size_t)(n0 + row) * ldb + k0 + kc, &Bs[row][kc]);
    }
    __syncthreads();
    bf16x8 af[4], bfr[4];
#pragma unroll
    for (int i = 0; i < 4; i++) af[i]  = *(const bf16x8*)(&As[wr + i * 16 + la][gq * 8]);
#pragma unroll
    for (int j = 0; j < 4; j++) bfr[j] = *(const bf16x8*)(&Bs[wc + j * 16 + la][gq * 8]);
#pragma unroll
    for (int i = 0; i < 4; i++)
#pragma unroll
      for (int j = 0; j < 4; j++)
        acc[i][j] = __builtin_amdgcn_mfma_f32_16x16x32_bf16(af[i], bfr[j], acc[i][j], 0, 0, 0);
    __syncthreads();
  }

#pragma unroll
  for (int i = 0; i < 4; i++) {
    int rowb = m0 + wr + i * 16 + gq * 4;
#pragma unroll
    for (int j = 0; j < 4; j++) {
      int col = n0 + wc + j * 16 + la;
      if (col >= N) continue;
      if (mode == 2) {
#pragma unroll
        for (int r = 0; r < 4; r++)
          ((float*)Cv)[(size_t)(rowb + r) * ldc + col] = acc[i][j][r];
      } else if (mode == 3) {
        s16x4 pk;
#pragma unroll
        for (int r = 0; r < 4; r++) {
          float v = acc[i][j][r] + bias[col];
          v = (v > 20.f) ? v : log1pf(__expf(v));
          pk[r] = f2bs(v);
        }
        *(s16x4*)((short*)Cv + (size_t)col * ldc + rowb) = pk;
      } else if (mode == 4) {
        if (col < DTR) {
#pragma unroll
          for (int r = 0; r < 4; r++)
            ((short*)Cv)[(size_t)(rowb + r) * ldc + col] = f2bs(acc[i][j][r]);
        } else {
          s16x4 pk;
#pragma unroll
          for (int r = 0; r < 4; r++) pk[r] = f2bs(acc[i][j][r]);
          *(s16x4*)((short*)Cv2 + (size_t)(col - DTR) * ldc2 + rowb) = pk;
        }
      } else if (mode == 5) {
        short* base = (col < DI) ? (short*)Cv : (short*)Cv2;
        int c = (col < DI) ? col : col - DI;
        int ld = (col < DI) ? ldc : ldc2;
#pragma unroll
        for (int r = 0; r < 4; r++)
          base[(size_t)(rowb + r) * ld + c] = f2bs(acc[i][j][r]);
      } else if (mode == 6) {
        // softplus + per-ROW bias, row-major bf16 store (col = t is lane-consecutive)
#pragma unroll
        for (int r = 0; r < 4; r++) {
          float v = acc[i][j][r] + bias[rowb + r];
          v = (v > 20.f) ? v : log1pf(__expf(v));
          ((short*)Cv)[(size_t)(rowb + r) * ldc + col] = f2bs(v);
        }
      } else { // mode 0: plain bf16 token-major
#pragma unroll
        for (int r = 0; r < 4; r++)
          ((short*)Cv)[(size_t)(rowb + r) * ldc + col] = f2bs(acc[i][j][r]);
      }
    }
  }
}

// ---------------------------------------------------------------------------
// depthwise causal conv1d (k=4) + bias + SiLU.  Reads xb[token][DI].
// ---------------------------------------------------------------------------
__global__ __launch_bounds__(256)
void conv_silu(const short* __restrict__ xb, const float* __restrict__ cw,
               const float* __restrict__ cb, short* __restrict__ xs)
{
  const int token = blockIdx.x;
  const int l = token & (L_ - 1);
  const int d0 = threadIdx.x * 8;

  float w[32];
#pragma unroll
  for (int i = 0; i < 8; i++) {
    float4 t = *(const float4*)(cw + (size_t)(d0 + i) * 4);
    w[i * 4 + 0] = t.x; w[i * 4 + 1] = t.y; w[i * 4 + 2] = t.z; w[i * 4 + 3] = t.w;
  }
  float acc[8];
  {
    float4 b0 = *(const float4*)(cb + d0);
    float4 b1 = *(const float4*)(cb + d0 + 4);
    acc[0] = b0.x; acc[1] = b0.y; acc[2] = b0.z; acc[3] = b0.w;
    acc[4] = b1.x; acc[5] = b1.y; acc[6] = b1.z; acc[7] = b1.w;
  }
#pragma unroll
  for (int j = 0; j < 4; j++) {
    int lj = l - 3 + j;
    if (lj >= 0) {
      bf16x8 xv = *(const bf16x8*)(xb + (size_t)(token - 3 + j) * DI + d0);
#pragma unroll
      for (int i = 0; i < 8; i++) acc[i] += w[i * 4 + j] * bf2f(xv[i]);
    }
  }
  union { bf16x8 v; short h[8]; } o;
#pragma unroll
  for (int i = 0; i < 8; i++) {
    float v = acc[i];
    o.h[i] = f2bs(v * sigmoidf_fast(v));
  }
  *(bf16x8*)(xs + (size_t)token * DI + d0) = o.v;
}

// ---------------------------------------------------------------------------
// selective scan, 16 lanes per (b,d) channel (one per state n), fused gating.
//  - dt from dT[d][t], B/C from dbcT[n][t] (contiguous 32B vec loads)
//  - u from xs[t][d] (scalar broadcast), res from resy[t][d] (per-lane)
//  - butterfly xor transpose-reduce: lane n ends with y(step l+n) -> full-wave
//    gate + scatter store.  u*D folded as u*D/16 per lane.
//  - 1-deep register double buffer (ping-pong) to hide load latency.
// ---------------------------------------------------------------------------
__global__ __launch_bounds__(256, 2)
void scan_kernel(const short* __restrict__ dT, const short* __restrict__ dbcT,
                 const short* __restrict__ xs, short* __restrict__ resy,
                 const float* __restrict__ A_log, const float* __restrict__ Dw,
                 const float* __restrict__ h0)
{
  const int lane = threadIdx.x & 63;
  const int grp = threadIdx.x >> 4, n = threadIdx.x & 15;
  const int ch = blockIdx.x * 16 + grp;          // ch = b*DI + d
  const int b = ch >> 11, d = ch & (DI - 1);
  const bool b3 = (lane & 8) != 0, b2 = (lane & 4) != 0,
             b1 = (lane & 2) != 0, b0 = (lane & 1) != 0;
  const float An = -__expf(A_log[d * NST + n]);
  const float Dd16 = Dw[d] * 0.0625f;            // D/16: summed 16x in reduce
  float h = h0[(size_t)ch * NST + n];

  const size_t t0 = (size_t)b * L_;
  const short* dRow = dT   + (size_t)d * NTOK + t0;
  const short* bRow = dbcT + (size_t)n * NTOK + t0;
  const short* cRow = bRow + (size_t)NST * NTOK;
  const short* uCol = xs   + t0 * DI + d;
  short*       yCol = resy + (t0 + n) * DI + d;  // res read / y write, per-lane row

  auto LOADB = [&](int lv, bf16x8& t0v, bf16x8& t1v, bf16x8& B0v, bf16x8& B1v,
                   bf16x8& C0v, bf16x8& C1v, short* ur, short& rr) {
    t0v = *(const bf16x8*)(dRow + lv);
    t1v = *(const bf16x8*)(dRow + lv + 8);
    B0v = *(const bf16x8*)(bRow + lv);
    B1v = *(const bf16x8*)(bRow + lv + 8);
    C0v = *(const bf16x8*)(cRow + lv);
    C1v = *(const bf16x8*)(cRow + lv + 8);
#pragma unroll
    for (int s = 0; s < 16; s++) ur[s] = uCol[(size_t)(lv + s) * DI];
    rr = yCol[(size_t)lv * DI];
  };

  auto STEP = [&](int lv, bf16x8 t0v, bf16x8 t1v, bf16x8 B0v, bf16x8 B1v,
                  bf16x8 C0v, bf16x8 C1v, const short* ur, short rr) {
    // ---- precompute (independent of h) ----
    float dA[16], w[16], g[16];
#pragma unroll
    for (int s = 0; s < 16; s++) {
      float dt = bf2f(s < 8 ? t0v[s] : t1v[s - 8]);
      float uu = bf2f(ur[s]);
      dA[s] = __expf(dt * An);
      g[s]  = uu * Dd16;
      w[s]  = dt * uu * bf2f(s < 8 ? B0v[s] : B1v[s - 8]);
    }
    // ---- serial chain (16 FMAs) + per-state output term ----
    float p[16];
#pragma unroll
    for (int s = 0; s < 16; s++) {
      h = __builtin_fmaf(dA[s], h, w[s]);
      p[s] = __builtin_fmaf(h, bf2f(s < 8 ? C0v[s] : C1v[s - 8]), g[s]);
    }
    // ---- butterfly transpose-reduce: lane n -> sum over states of p[n] ----
    float q8[8];
#pragma unroll
    for (int i = 0; i < 8; i++) {
      float keep = b3 ? p[i + 8] : p[i];
      float send = b3 ? p[i]     : p[i + 8];
      q8[i] = keep + swz_xor8(send);
    }
    float q4[4];
#pragma unroll
    for (int i = 0; i < 4; i++) {
      float keep = b2 ? q8[i + 4] : q8[i];
      float send = b2 ? q8[i]     : q8[i + 4];
      q4[i] = keep + swz_xor4(send);
    }
    float q2[2];
#pragma unroll
    for (int i = 0; i < 2; i++) {
      float keep = b1 ? q4[i + 2] : q4[i];
      float send = b1 ? q4[i]     : q4[i + 2];
      q2[i] = keep + qperm<0x4E>(send);       // quad_perm [2,3,0,1] = xor 2
    }
    float keep = b0 ? q2[1] : q2[0];
    float send = b0 ? q2[0] : q2[1];
    float ysum = keep + qperm<0xB1>(send);     // quad_perm [1,0,3,2] = xor 1
    // ---- full-wave gate + scatter store (lane n owns step lv+n) ----
    float r = bf2f(rr);
    float yv = ysum * (r * sigmoidf_fast(r));
    yCol[(size_t)lv * DI] = f2bs(yv);
  };

  bf16x8 a0, a1, a2, a3, a4, a5; short ua[16]; short ra;
  bf16x8 c0, c1, c2, c3, c4, c5; short ub[16]; short rb;
  LOADB(0, a0, a1, a2, a3, a4, a5, ua, ra);
  for (int l = 0; l < L_; l += 32) {
    LOADB(l + 16, c0, c1, c2, c3, c4, c5, ub, rb);
    STEP(l, a0, a1, a2, a3, a4, a5, ua, ra);
    if (l + 32 < L_) LOADB(l + 32, a0, a1, a2, a3, a4, a5, ua, ra);
    STEP(l + 16, c0, c1, c2, c3, c4, c5, ub, rb);
  }
}

// ---------------------------------------------------------------------------
extern "C" void kernel_launch(void* const* d_in, const int* in_sizes, int n_in,
                              void* d_out, int out_size, void* d_ws, size_t ws_size,
                              hipStream_t stream)
{
  const float* u        = (const float*)d_in[0];
  const float* hiddens  = (const float*)d_in[1];
  const float* in_proj  = (const float*)d_in[2];
  const float* conv_w   = (const float*)d_in[3];
  const float* conv_b   = (const float*)d_in[4];
  const float* x_proj   = (const float*)d_in[5];   // (2048, 96)
  const float* dt_proj  = (const float*)d_in[6];   // (64, 2048)
  const float* dt_bias  = (const float*)d_in[7];
  const float* A_log    = (const float*)d_in[8];
  const float* Dw       = (const float*)d_in[9];
  const float* out_proj = (const float*)d_in[10];
  float* out = (float*)d_out;

  // workspace: ~74 MiB (under the previously proven 78 MiB)
  char* w = (char*)d_ws;
  short* Wt1  = (short*)w;                                 // in_proj^T (4096x1024), 8 MiB
  short* Wt4  = Wt1;                                       // out_proj^T reuses Wt1 after GEMM1
  w += (size_t)4096 * 1024 * 2;
  short* Wxp  = (short*)w; w += (size_t)128  * 2048 * 2;   // x_proj^T, padded to 128 rows
  short* dtw  = (short*)w; w += (size_t)2048 * 64   * 2;   // dt_proj^T  (2048 x 64)
  short* xbuf = (short*)w; w += (size_t)NTOK * DI   * 2;   // x (token-major) -> dT (chan-major)
  short* resy = (short*)w; w += (size_t)NTOK * DI   * 2;   // res (token-major) -> y in-place
  short* dbc  = (short*)w; w += (size_t)NTOK * DTR  * 2;   // dt_rank part, token-major (8192x64)
  short* dbcT = (short*)w; w += (size_t)32   * NTOK * 2;   // B|C transposed (32 x 8192)
  short* ub   = (short*)d_out;                             // u in bf16 (16 MiB, dead after GEMM1)
  short* xs   = (short*)d_out;                             // conv out borrows d_out after GEMM1
  short* dT   = xbuf;                                      // delta^T overlays dead x

  dim3 tb(32, 8);
  cvt_f2b<<<4096, 256, 0, stream>>>(u, ub);                // u -> bf16 (8192x1024)
  transpose_f2b<<<dim3(32, 128), tb, 0, stream>>>(in_proj,  Wt1, 1024, 4096, 4096, 1024);
  transpose_f2b<<<dim3(64, 3),   tb, 0, stream>>>(x_proj,   Wxp, 2048, 96,   96,   2048);
  transpose_f2b<<<dim3(2, 64),   tb, 0, stream>>>(dt_proj,  dtw, 64,   2048, 2048, 64);

  // GEMM1: [x | res] = ub @ in_proj, split into xbuf / resy (token-major, ld=DI)
  gemm_bt<<<dim3(64, 32), 256, 0, stream>>>(ub, Wt1, xbuf, resy, nullptr,
                                            4096, 1024, 1024, 1024, DI, DI, 5);
  // out_proj^T into the now-free Wt1 region (stream-ordered after GEMM1)
  transpose_f2b<<<dim3(64, 32),  tb, 0, stream>>>(out_proj, Wt4, 2048, 1024, 1024, 2048);
  // conv + silu -> xs (token-major, in d_out; ub dead from here)
  conv_silu<<<NTOK, 256, 0, stream>>>(xbuf, conv_w, conv_b, xs);
  // GEMM2: dbc = xs @ x_proj; dt-rank cols token-major, B/C cols transposed to dbcT
  gemm_bt<<<dim3(64, 1), 256, 0, stream>>>(xs, Wxp, dbc, dbcT, nullptr,
                                           96, 2048, 2048, 2048, DTR, NTOK, 4);
  // GEMM3 (swapped operands): dT[d][t] = softplus(dtw[d,:] . dbc[t,:] + bias[d])
  // A = dtw (2048x64), Bt = dbc (8192x64) -> row-major coalesced store, no scatter.
  gemm_bt<<<dim3(16, 64), 256, 0, stream>>>(dtw, dbc, dT, nullptr, dt_bias,
                                            NTOK, 64, 64, 64, NTOK, 0, 6);
  // selective scan + gated epilogue: y overwrites res in-place (token-major)
  scan_kernel<<<512, 256, 0, stream>>>(dT, dbcT, xs, resy, A_log, Dw, hiddens);
  // GEMM4: out = y @ out_proj  (8192 x 1024, f32 store)
  gemm_bt<<<dim3(64, 8), 256, 0, stream>>>(resy, Wt4, out, nullptr, nullptr,
                                           1024, 2048, 2048, 2048, 1024, 0, 2);
}

// Round 4
// 646.015 us; speedup vs baseline: 1.5092x; 1.1373x over previous
//
#include <hip/hip_runtime.h>
#include <hip/hip_bf16.h>
#include <cstddef>

#define B_   4
#define L_   2048
#define DM   1024
#define DI   2048
#define NST  16
#define DTR  64        // (1024+15)//16 = 64
#define NBC  96        // DTR + 2*NST
#define NTOK 8192      // B_*L_

using bf16 = __hip_bfloat16;
typedef __attribute__((ext_vector_type(8))) short bf16x8;
typedef __attribute__((ext_vector_type(4))) short s16x4;
typedef __attribute__((ext_vector_type(4))) float f32x4;

__device__ __forceinline__ float bf2f(short s) {
  unsigned u = ((unsigned)(unsigned short)s) << 16;
  float f; __builtin_memcpy(&f, &u, 4); return f;
}
__device__ __forceinline__ short f2bs(float f) {
  __hip_bfloat16 h = __float2bfloat16(f);
  short s; __builtin_memcpy(&s, &h, 2); return s;
}
__device__ __forceinline__ float sigmoidf_fast(float x) {
  return 1.f / (1.f + __expf(-x));
}

// async global->LDS, 16B per lane (dest must be wave-uniform base + lane*16)
#define GLD16(g, l) __builtin_amdgcn_global_load_lds( \
  (const __attribute__((address_space(1))) unsigned int*)(g), \
  (__attribute__((address_space(3))) unsigned int*)(l), 16, 0, 0)

// cross-lane xor shuffles for the 16-state butterfly reduce
__device__ __forceinline__ float swz_xor8(float x) {
  return __builtin_bit_cast(float,
    __builtin_amdgcn_ds_swizzle(__builtin_bit_cast(int, x), 0x201F)); // lane ^= 8
}
__device__ __forceinline__ float swz_xor4(float x) {
  return __builtin_bit_cast(float,
    __builtin_amdgcn_ds_swizzle(__builtin_bit_cast(int, x), 0x101F)); // lane ^= 4
}
template<int CTRL>
__device__ __forceinline__ float qperm(float x) {  // DPP quad_perm, full VALU rate
  return __builtin_bit_cast(float,
    __builtin_amdgcn_update_dpp(0, __builtin_bit_cast(int, x), CTRL, 0xf, 0xf, false));
}
// broadcast lane (group_base | S) to all 16 lanes of the group (BitMode:
// src = (lane & 0x10) | S, applied per 32-lane half)
template<int S>
__device__ __forceinline__ float swz_bcast16(float x) {
  return __builtin_bit_cast(float,
    __builtin_amdgcn_ds_swizzle(__builtin_bit_cast(int, x), (S << 5) | 0x10));
}

// ---------------------------------------------------------------------------
// f32 -> bf16 bulk convert (n elements = grid*256*8 exactly)
// ---------------------------------------------------------------------------
__global__ __launch_bounds__(256)
void cvt_f2b(const float* __restrict__ in, short* __restrict__ out)
{
  const size_t i = ((size_t)blockIdx.x * 256 + threadIdx.x) * 8;
  float4 a0 = *(const float4*)(in + i);
  float4 a1 = *(const float4*)(in + i + 4);
  union { bf16x8 v; short h[8]; } o;
  o.h[0] = f2bs(a0.x); o.h[1] = f2bs(a0.y); o.h[2] = f2bs(a0.z); o.h[3] = f2bs(a0.w);
  o.h[4] = f2bs(a1.x); o.h[5] = f2bs(a1.y); o.h[6] = f2bs(a1.z); o.h[7] = f2bs(a1.w);
  *(bf16x8*)(out + i) = o.v;
}

// ---------------------------------------------------------------------------
// transpose f32 in -> bf16 out, zero-pad: out[c][r] = (r<R&&c<Cc) ? in[r*lin+c] : 0
// ---------------------------------------------------------------------------
__global__ __launch_bounds__(256)
void transpose_f2b(const float* __restrict__ in, short* __restrict__ out,
                   int R, int Cc, int lin, int lout)
{
  __shared__ short t[32][33];
  const int r0 = blockIdx.x * 32, c0 = blockIdx.y * 32;
  const int tx = threadIdx.x, ty = threadIdx.y;
#pragma unroll
  for (int i = 0; i < 4; i++) {
    int r = r0 + ty + i * 8;
    int c = c0 + tx;
    short v = 0;
    if (r < R && c < Cc) v = f2bs(in[(size_t)r * lin + c]);
    t[ty + i * 8][tx] = v;
  }
  __syncthreads();
#pragma unroll
  for (int i = 0; i < 4; i++) {
    int c = c0 + ty + i * 8;
    int r = r0 + tx;
    if (c < Cc && r < lout) out[(size_t)c * lout + r] = t[tx][ty + i * 8];
  }
}

// ---------------------------------------------------------------------------
// bf16 MFMA GEMM, C[M x N] = A[M x K] * Bt[N x K]^T.  128x128 tile, BK=32,
// 4 waves each 64x64 (4x4 of 16x16x32 MFMA).  global_load_lds (16B) staging,
// linear LDS tiles (m97 structure).  A/B tile rows are read UNGUARDED: both
// buffers must be allocated with >= ceil128 rows (they are).
// XCD-aware bijective block swizzle (requires gridDim.x*gridDim.y % 8 == 0).
// mode 2: f32 token-major store.
// mode 4: col<DTR -> bf16 token-major to Cv (ldc); col>=DTR -> bf16 transposed to Cv2 (ldc2)
// mode 5: col<DI  -> bf16 token-major to Cv (ldc); col>=DI  -> token-major to Cv2 (ldc2)
// mode 6: softplus(v + bias[ROW]) -> bf16 row-major store (ldc)  [GEMM3 swapped form]
// ---------------------------------------------------------------------------
__global__ __launch_bounds__(256)
void gemm_bt(const short* __restrict__ A, const short* __restrict__ Bt,
             void* __restrict__ Cv, void* __restrict__ Cv2, const float* __restrict__ bias,
             int N, int K, int lda, int ldb, int ldc, int ldc2, int mode)
{
  __shared__ short As[128][32];
  __shared__ short Bs[128][32];
  // ---- XCD swizzle: dispatch i -> XCD i%8; give XCD k contiguous work chunk ----
  const int gx = gridDim.x;
  const int nwg = gx * gridDim.y;
  const int lid = blockIdx.x + gx * blockIdx.y;
  const int cpx = nwg >> 3;                       // nwg % 8 == 0 for all call sites
  const int swz = (lid & 7) * cpx + (lid >> 3);
  const int m0 = (swz % gx) * 128;
  const int n0 = (swz / gx) * 128;
  const int tid  = threadIdx.x;
  const int wave = tid >> 6, lane = tid & 63;
  const int wr = (wave >> 1) * 64, wc = (wave & 1) * 64;
  const int la = lane & 15, gq = lane >> 4;
  f32x4 acc[4][4] = {};

  for (int k0 = 0; k0 < K; k0 += 32) {
#pragma unroll
    for (int i = 0; i < 2; i++) {
      int idx = tid + i * 256;
      int row = idx >> 2, kc = (idx & 3) * 8;
      GLD16(A  + (size_t)(m0 + row) * lda + k0 + kc, &As[row][kc]);
      GLD16(Bt + (size_t)(n0 + row) * ldb + k0 + kc, &Bs[row][kc]);
    }
    __syncthreads();
    bf16x8 af[4], bfr[4];
#pragma unroll
    for (int i = 0; i < 4; i++) af[i]  = *(const bf16x8*)(&As[wr + i * 16 + la][gq * 8]);
#pragma unroll
    for (int j = 0; j < 4; j++) bfr[j] = *(const bf16x8*)(&Bs[wc + j * 16 + la][gq * 8]);
#pragma unroll
    for (int i = 0; i < 4; i++)
#pragma unroll
      for (int j = 0; j < 4; j++)
        acc[i][j] = __builtin_amdgcn_mfma_f32_16x16x32_bf16(af[i], bfr[j], acc[i][j], 0, 0, 0);
    __syncthreads();
  }

#pragma unroll
  for (int i = 0; i < 4; i++) {
    int rowb = m0 + wr + i * 16 + gq * 4;
#pragma unroll
    for (int j = 0; j < 4; j++) {
      int col = n0 + wc + j * 16 + la;
      if (col >= N) continue;
      if (mode == 2) {
#pragma unroll
        for (int r = 0; r < 4; r++)
          ((float*)Cv)[(size_t)(rowb + r) * ldc + col] = acc[i][j][r];
      } else if (mode == 4) {
        if (col < DTR) {
#pragma unroll
          for (int r = 0; r < 4; r++)
            ((short*)Cv)[(size_t)(rowb + r) * ldc + col] = f2bs(acc[i][j][r]);
        } else {
          s16x4 pk;
#pragma unroll
          for (int r = 0; r < 4; r++) pk[r] = f2bs(acc[i][j][r]);
          *(s16x4*)((short*)Cv2 + (size_t)(col - DTR) * ldc2 + rowb) = pk;
        }
      } else if (mode == 5) {
        short* base = (col < DI) ? (short*)Cv : (short*)Cv2;
        int c = (col < DI) ? col : col - DI;
        int ld = (col < DI) ? ldc : ldc2;
#pragma unroll
        for (int r = 0; r < 4; r++)
          base[(size_t)(rowb + r) * ld + c] = f2bs(acc[i][j][r]);
      } else if (mode == 6) {
        // softplus + per-ROW bias, row-major bf16 store (col = t is lane-consecutive)
        // softplus via exp2/log2 (no libm log1pf): ln(1+e^v) = ln2*log2(1+2^(v*log2e))
#pragma unroll
        for (int r = 0; r < 4; r++) {
          float v = acc[i][j][r] + bias[rowb + r];
          float e = exp2f(v * 1.44269504f);
          v = (v > 20.f) ? v : 0.69314718f * __log2f(1.f + e);
          ((short*)Cv)[(size_t)(rowb + r) * ldc + col] = f2bs(v);
        }
      } else { // mode 0: plain bf16 token-major
#pragma unroll
        for (int r = 0; r < 4; r++)
          ((short*)Cv)[(size_t)(rowb + r) * ldc + col] = f2bs(acc[i][j][r]);
      }
    }
  }
}

// ---------------------------------------------------------------------------
// depthwise causal conv1d (k=4) + bias + SiLU.  Reads xb[token][DI].
// ---------------------------------------------------------------------------
__global__ __launch_bounds__(256)
void conv_silu(const short* __restrict__ xb, const float* __restrict__ cw,
               const float* __restrict__ cb, short* __restrict__ xs)
{
  const int token = blockIdx.x;
  const int l = token & (L_ - 1);
  const int d0 = threadIdx.x * 8;

  float w[32];
#pragma unroll
  for (int i = 0; i < 8; i++) {
    float4 t = *(const float4*)(cw + (size_t)(d0 + i) * 4);
    w[i * 4 + 0] = t.x; w[i * 4 + 1] = t.y; w[i * 4 + 2] = t.z; w[i * 4 + 3] = t.w;
  }
  float acc[8];
  {
    float4 b0 = *(const float4*)(cb + d0);
    float4 b1 = *(const float4*)(cb + d0 + 4);
    acc[0] = b0.x; acc[1] = b0.y; acc[2] = b0.z; acc[3] = b0.w;
    acc[4] = b1.x; acc[5] = b1.y; acc[6] = b1.z; acc[7] = b1.w;
  }
#pragma unroll
  for (int j = 0; j < 4; j++) {
    int lj = l - 3 + j;
    if (lj >= 0) {
      bf16x8 xv = *(const bf16x8*)(xb + (size_t)(token - 3 + j) * DI + d0);
#pragma unroll
      for (int i = 0; i < 8; i++) acc[i] += w[i * 4 + j] * bf2f(xv[i]);
    }
  }
  union { bf16x8 v; short h[8]; } o;
#pragma unroll
  for (int i = 0; i < 8; i++) {
    float v = acc[i];
    o.h[i] = f2bs(v * sigmoidf_fast(v));
  }
  *(bf16x8*)(xs + (size_t)token * DI + d0) = o.v;
}

// ---------------------------------------------------------------------------
// selective scan, 16 lanes per (b,d) channel (one per state n), fused gating.
//  - dt from dT[d][t], B/C from dbcT[n][t] (contiguous 32B vec loads)
//  - u: lane n loads ONLY u[lv+n][d] (1 VMEM/batch), then 16 compile-time
//    ds_swizzle broadcasts distribute u[s] to the group at VALU rate
//  - dA = exp2f(dt * An*log2e): log2e folded into An once
//  - u*D applied AFTER the reduce (lane n owns step lv+n; its own u IS u[lv+n])
//  - butterfly xor transpose-reduce -> full-wave gate + scatter store
//  - 1-deep register double buffer (ping-pong) to hide load latency
// ---------------------------------------------------------------------------
__global__ __launch_bounds__(256, 2)
void scan_kernel(const short* __restrict__ dT, const short* __restrict__ dbcT,
                 const short* __restrict__ xs, short* __restrict__ resy,
                 const float* __restrict__ A_log, const float* __restrict__ Dw,
                 const float* __restrict__ h0)
{
  const int lane = threadIdx.x & 63;
  const int grp = threadIdx.x >> 4, n = threadIdx.x & 15;
  const int ch = blockIdx.x * 16 + grp;          // ch = b*DI + d
  const int b = ch >> 11, d = ch & (DI - 1);
  const bool b3 = (lane & 8) != 0, b2 = (lane & 4) != 0,
             b1 = (lane & 2) != 0, b0 = (lane & 1) != 0;
  const float An2 = -__expf(A_log[d * NST + n]) * 1.44269504f;  // An * log2(e)
  const float Dd = Dw[d];
  float h = h0[(size_t)ch * NST + n];

  const size_t t0 = (size_t)b * L_;
  const short* dRow = dT   + (size_t)d * NTOK + t0;
  const short* bRow = dbcT + (size_t)n * NTOK + t0;
  const short* cRow = bRow + (size_t)NST * NTOK;
  const short* uLn  = xs   + (t0 + n) * DI + d;  // per-lane u row (lane n = step lv+n)
  short*       yCol = resy + (t0 + n) * DI + d;  // res read / y write, per-lane row

  auto LOADB = [&](int lv, bf16x8& t0v, bf16x8& t1v, bf16x8& B0v, bf16x8& B1v,
                   bf16x8& C0v, bf16x8& C1v, short& uo, short& rr) {
    t0v = *(const bf16x8*)(dRow + lv);
    t1v = *(const bf16x8*)(dRow + lv + 8);
    B0v = *(const bf16x8*)(bRow + lv);
    B1v = *(const bf16x8*)(bRow + lv + 8);
    C0v = *(const bf16x8*)(cRow + lv);
    C1v = *(const bf16x8*)(cRow + lv + 8);
    uo = uLn[(size_t)lv * DI];                   // u[lv+n][d], one load per lane
    rr = yCol[(size_t)lv * DI];
  };

  auto STEP = [&](int lv, bf16x8 t0v, bf16x8 t1v, bf16x8 B0v, bf16x8 B1v,
                  bf16x8 C0v, bf16x8 C1v, short uo, short rr) {
    const float uown = bf2f(uo);
    // ---- broadcast u[s] to all lanes of the group (VALU-rate, no VMEM) ----
    float uf[16];
    uf[0]  = swz_bcast16<0>(uown);   uf[1]  = swz_bcast16<1>(uown);
    uf[2]  = swz_bcast16<2>(uown);   uf[3]  = swz_bcast16<3>(uown);
    uf[4]  = swz_bcast16<4>(uown);   uf[5]  = swz_bcast16<5>(uown);
    uf[6]  = swz_bcast16<6>(uown);   uf[7]  = swz_bcast16<7>(uown);
    uf[8]  = swz_bcast16<8>(uown);   uf[9]  = swz_bcast16<9>(uown);
    uf[10] = swz_bcast16<10>(uown);  uf[11] = swz_bcast16<11>(uown);
    uf[12] = swz_bcast16<12>(uown);  uf[13] = swz_bcast16<13>(uown);
    uf[14] = swz_bcast16<14>(uown);  uf[15] = swz_bcast16<15>(uown);
    // ---- precompute (independent of h) ----
    float dA[16], w[16];
#pragma unroll
    for (int s = 0; s < 16; s++) {
      float dt = bf2f(s < 8 ? t0v[s] : t1v[s - 8]);
      dA[s] = exp2f(dt * An2);
      w[s]  = dt * uf[s] * bf2f(s < 8 ? B0v[s] : B1v[s - 8]);
    }
    // ---- serial chain (16 FMAs) + per-state output term ----
    float p[16];
#pragma unroll
    for (int s = 0; s < 16; s++) {
      h = __builtin_fmaf(dA[s], h, w[s]);
      p[s] = h * bf2f(s < 8 ? C0v[s] : C1v[s - 8]);
    }
    // ---- butterfly transpose-reduce: lane n -> sum over states of p[n] ----
    float q8[8];
#pragma unroll
    for (int i = 0; i < 8; i++) {
      float keep = b3 ? p[i + 8] : p[i];
      float send = b3 ? p[i]     : p[i + 8];
      q8[i] = keep + swz_xor8(send);
    }
    float q4[4];
#pragma unroll
    for (int i = 0; i < 4; i++) {
      float keep = b2 ? q8[i + 4] : q8[i];
      float send = b2 ? q8[i]     : q8[i + 4];
      q4[i] = keep + swz_xor4(send);
    }
    float q2[2];
#pragma unroll
    for (int i = 0; i < 2; i++) {
      float keep = b1 ? q4[i + 2] : q4[i];
      float send = b1 ? q4[i]     : q4[i + 2];
      q2[i] = keep + qperm<0x4E>(send);       // quad_perm [2,3,0,1] = xor 2
    }
    float keep = b0 ? q2[1] : q2[0];
    float send = b0 ? q2[0] : q2[1];
    float ysum = keep + qperm<0xB1>(send);     // quad_perm [1,0,3,2] = xor 1
    // ---- skip term + gate + store (lane n owns step lv+n; uown = u[lv+n]) ----
    ysum = __builtin_fmaf(uown, Dd, ysum);
    float r = bf2f(rr);
    float yv = ysum * (r * sigmoidf_fast(r));
    yCol[(size_t)lv * DI] = f2bs(yv);
  };

  bf16x8 a0, a1, a2, a3, a4, a5; short ua, ra;
  bf16x8 c0, c1, c2, c3, c4, c5; short ub, rb;
  LOADB(0, a0, a1, a2, a3, a4, a5, ua, ra);
  for (int l = 0; l < L_; l += 32) {
    LOADB(l + 16, c0, c1, c2, c3, c4, c5, ub, rb);
    STEP(l, a0, a1, a2, a3, a4, a5, ua, ra);
    if (l + 32 < L_) LOADB(l + 32, a0, a1, a2, a3, a4, a5, ua, ra);
    STEP(l + 16, c0, c1, c2, c3, c4, c5, ub, rb);
  }
}

// ---------------------------------------------------------------------------
extern "C" void kernel_launch(void* const* d_in, const int* in_sizes, int n_in,
                              void* d_out, int out_size, void* d_ws, size_t ws_size,
                              hipStream_t stream)
{
  const float* u        = (const float*)d_in[0];
  const float* hiddens  = (const float*)d_in[1];
  const float* in_proj  = (const float*)d_in[2];
  const float* conv_w   = (const float*)d_in[3];
  const float* conv_b   = (const float*)d_in[4];
  const float* x_proj   = (const float*)d_in[5];   // (2048, 96)
  const float* dt_proj  = (const float*)d_in[6];   // (64, 2048)
  const float* dt_bias  = (const float*)d_in[7];
  const float* A_log    = (const float*)d_in[8];
  const float* Dw       = (const float*)d_in[9];
  const float* out_proj = (const float*)d_in[10];
  float* out = (float*)d_out;

  // workspace: ~74 MiB (under the previously proven 78 MiB)
  char* w = (char*)d_ws;
  short* Wt1  = (short*)w;                                 // in_proj^T (4096x1024), 8 MiB
  short* Wt4  = Wt1;                                       // out_proj^T reuses Wt1 after GEMM1
  w += (size_t)4096 * 1024 * 2;
  short* Wxp  = (short*)w; w += (size_t)128  * 2048 * 2;   // x_proj^T, padded to 128 rows
  short* dtw  = (short*)w; w += (size_t)2048 * 64   * 2;   // dt_proj^T  (2048 x 64)
  short* xbuf = (short*)w; w += (size_t)NTOK * DI   * 2;   // x (token-major) -> dT (chan-major)
  short* resy = (short*)w; w += (size_t)NTOK * DI   * 2;   // res (token-major) -> y in-place
  short* dbc  = (short*)w; w += (size_t)NTOK * DTR  * 2;   // dt_rank part, token-major (8192x64)
  short* dbcT = (short*)w; w += (size_t)32   * NTOK * 2;   // B|C transposed (32 x 8192)
  short* ub   = (short*)d_out;                             // u in bf16 (16 MiB, dead after GEMM1)
  short* xs   = (short*)d_out;                             // conv out borrows d_out after GEMM1
  short* dT   = xbuf;                                      // delta^T overlays dead x

  dim3 tb(32, 8);
  cvt_f2b<<<4096, 256, 0, stream>>>(u, ub);                // u -> bf16 (8192x1024)
  transpose_f2b<<<dim3(32, 128), tb, 0, stream>>>(in_proj,  Wt1, 1024, 4096, 4096, 1024);
  transpose_f2b<<<dim3(64, 3),   tb, 0, stream>>>(x_proj,   Wxp, 2048, 96,   96,   2048);
  transpose_f2b<<<dim3(2, 64),   tb, 0, stream>>>(dt_proj,  dtw, 64,   2048, 2048, 64);

  // GEMM1: [x | res] = ub @ in_proj, split into xbuf / resy (token-major, ld=DI)
  gemm_bt<<<dim3(64, 32), 256, 0, stream>>>(ub, Wt1, xbuf, resy, nullptr,
                                            4096, 1024, 1024, 1024, DI, DI, 5);
  // out_proj^T into the now-free Wt1 region (stream-ordered after GEMM1)
  transpose_f2b<<<dim3(64, 32),  tb, 0, stream>>>(out_proj, Wt4, 2048, 1024, 1024, 2048);
  // conv + silu -> xs (token-major, in d_out; ub dead from here)
  conv_silu<<<NTOK, 256, 0, stream>>>(xbuf, conv_w, conv_b, xs);
  // GEMM2: dbc = xs @ x_proj; dt-rank cols token-major, B/C cols transposed to dbcT
  gemm_bt<<<dim3(64, 1), 256, 0, stream>>>(xs, Wxp, dbc, dbcT, nullptr,
                                           96, 2048, 2048, 2048, DTR, NTOK, 4);
  // GEMM3 (swapped operands): dT[d][t] = softplus(dtw[d,:] . dbc[t,:] + bias[d])
  gemm_bt<<<dim3(16, 64), 256, 0, stream>>>(dtw, dbc, dT, nullptr, dt_bias,
                                            NTOK, 64, 64, 64, NTOK, 0, 6);
  // selective scan + gated epilogue: y overwrites res in-place (token-major)
  scan_kernel<<<512, 256, 0, stream>>>(dT, dbcT, xs, resy, A_log, Dw, hiddens);
  // GEMM4: out = y @ out_proj  (8192 x 1024, f32 store)
  gemm_bt<<<dim3(64, 8), 256, 0, stream>>>(resy, Wt4, out, nullptr, nullptr,
                                           1024, 2048, 2048, 2048, 1024, 0, 2);
}

// Round 5
// 634.418 us; speedup vs baseline: 1.5368x; 1.0183x over previous
//
#include <hip/hip_runtime.h>
#include <hip/hip_bf16.h>
#include <cstddef>

#define B_   4
#define L_   2048
#define DM   1024
#define DI   2048
#define NST  16
#define DTR  64        // (1024+15)//16 = 64
#define NBC  96        // DTR + 2*NST
#define NTOK 8192      // B_*L_

using bf16 = __hip_bfloat16;
typedef __attribute__((ext_vector_type(8))) short bf16x8;
typedef __attribute__((ext_vector_type(4))) short s16x4;
typedef __attribute__((ext_vector_type(4))) float f32x4;

__device__ __forceinline__ float bf2f(short s) {
  unsigned u = ((unsigned)(unsigned short)s) << 16;
  float f; __builtin_memcpy(&f, &u, 4); return f;
}
__device__ __forceinline__ short f2bs(float f) {
  __hip_bfloat16 h = __float2bfloat16(f);
  short s; __builtin_memcpy(&s, &h, 2); return s;
}
__device__ __forceinline__ float sigmoidf_fast(float x) {
  return 1.f / (1.f + __expf(-x));
}

// async global->LDS, 16B per lane (dest must be wave-uniform base + lane*16)
#define GLD16(g, l) __builtin_amdgcn_global_load_lds( \
  (const __attribute__((address_space(1))) unsigned int*)(g), \
  (__attribute__((address_space(3))) unsigned int*)(l), 16, 0, 0)

// cross-lane xor shuffles for the 16-state butterfly reduce
__device__ __forceinline__ float swz_xor8(float x) {
  return __builtin_bit_cast(float,
    __builtin_amdgcn_ds_swizzle(__builtin_bit_cast(int, x), 0x201F)); // lane ^= 8
}
__device__ __forceinline__ float swz_xor4(float x) {
  return __builtin_bit_cast(float,
    __builtin_amdgcn_ds_swizzle(__builtin_bit_cast(int, x), 0x101F)); // lane ^= 4
}
template<int CTRL>
__device__ __forceinline__ float qperm(float x) {  // DPP quad_perm, full VALU rate
  return __builtin_bit_cast(float,
    __builtin_amdgcn_update_dpp(0, __builtin_bit_cast(int, x), CTRL, 0xf, 0xf, false));
}
// broadcast lane (group_base | S) to all 16 lanes of the group (BitMode:
// src = (lane & 0x10) | S, applied per 32-lane half)
template<int S>
__device__ __forceinline__ float swz_bcast16(float x) {
  return __builtin_bit_cast(float,
    __builtin_amdgcn_ds_swizzle(__builtin_bit_cast(int, x), (S << 5) | 0x10));
}

// ---------------------------------------------------------------------------
// f32 -> bf16 bulk convert (n elements = grid*256*8 exactly)
// ---------------------------------------------------------------------------
__global__ __launch_bounds__(256)
void cvt_f2b(const float* __restrict__ in, short* __restrict__ out)
{
  const size_t i = ((size_t)blockIdx.x * 256 + threadIdx.x) * 8;
  float4 a0 = *(const float4*)(in + i);
  float4 a1 = *(const float4*)(in + i + 4);
  union { bf16x8 v; short h[8]; } o;
  o.h[0] = f2bs(a0.x); o.h[1] = f2bs(a0.y); o.h[2] = f2bs(a0.z); o.h[3] = f2bs(a0.w);
  o.h[4] = f2bs(a1.x); o.h[5] = f2bs(a1.y); o.h[6] = f2bs(a1.z); o.h[7] = f2bs(a1.w);
  *(bf16x8*)(out + i) = o.v;
}

// ---------------------------------------------------------------------------
// transpose f32 in -> bf16 out, zero-pad: out[c][r] = (r<R&&c<Cc) ? in[r*lin+c] : 0
// ---------------------------------------------------------------------------
__global__ __launch_bounds__(256)
void transpose_f2b(const float* __restrict__ in, short* __restrict__ out,
                   int R, int Cc, int lin, int lout)
{
  __shared__ short t[32][33];
  const int r0 = blockIdx.x * 32, c0 = blockIdx.y * 32;
  const int tx = threadIdx.x, ty = threadIdx.y;
#pragma unroll
  for (int i = 0; i < 4; i++) {
    int r = r0 + ty + i * 8;
    int c = c0 + tx;
    short v = 0;
    if (r < R && c < Cc) v = f2bs(in[(size_t)r * lin + c]);
    t[ty + i * 8][tx] = v;
  }
  __syncthreads();
#pragma unroll
  for (int i = 0; i < 4; i++) {
    int c = c0 + ty + i * 8;
    int r = r0 + tx;
    if (c < Cc && r < lout) out[(size_t)c * lout + r] = t[tx][ty + i * 8];
  }
}

// ---------------------------------------------------------------------------
// bf16 MFMA GEMM, C[M x N] = A[M x K] * Bt[N x K]^T.  128x128 tile, BK=64
// (2 barriers per 32 MFMAs instead of per 16 -> half the vmcnt drains),
// 4 waves each 64x64 (4x4 of 16x16x32 MFMA).  global_load_lds (16B) staging,
// linear LDS tiles (m97 structure).  A/B tile rows are read UNGUARDED: both
// buffers must be allocated with >= ceil128 rows (they are).  K % 64 == 0.
// XCD-aware bijective block swizzle (requires gridDim.x*gridDim.y % 8 == 0).
// mode 2: f32 token-major store.
// mode 4: col<DTR -> bf16 token-major to Cv (ldc); col>=DTR -> bf16 transposed to Cv2 (ldc2)
// mode 5: col<DI  -> bf16 token-major to Cv (ldc); col>=DI  -> token-major to Cv2 (ldc2)
// mode 6: softplus(v + bias[ROW]) -> bf16 row-major store (ldc)  [GEMM3 swapped form]
// ---------------------------------------------------------------------------
__global__ __launch_bounds__(256)
void gemm_bt(const short* __restrict__ A, const short* __restrict__ Bt,
             void* __restrict__ Cv, void* __restrict__ Cv2, const float* __restrict__ bias,
             int N, int K, int lda, int ldb, int ldc, int ldc2, int mode)
{
  __shared__ short As[128][64];
  __shared__ short Bs[128][64];
  // ---- XCD swizzle: dispatch i -> XCD i%8; give XCD k contiguous work chunk ----
  const int gx = gridDim.x;
  const int nwg = gx * gridDim.y;
  const int lid = blockIdx.x + gx * blockIdx.y;
  const int cpx = nwg >> 3;                       // nwg % 8 == 0 for all call sites
  const int swz = (lid & 7) * cpx + (lid >> 3);
  const int m0 = (swz % gx) * 128;
  const int n0 = (swz / gx) * 128;
  const int tid  = threadIdx.x;
  const int wave = tid >> 6, lane = tid & 63;
  const int wr = (wave >> 1) * 64, wc = (wave & 1) * 64;
  const int la = lane & 15, gq = lane >> 4;
  f32x4 acc[4][4] = {};

  for (int k0 = 0; k0 < K; k0 += 64) {
#pragma unroll
    for (int i = 0; i < 4; i++) {
      int idx = tid + i * 256;                    // 0..1023
      int row = idx >> 3, kc = (idx & 7) * 8;     // linear: addr = idx*16B
      GLD16(A  + (size_t)(m0 + row) * lda + k0 + kc, &As[row][kc]);
      GLD16(Bt + (size_t)(n0 + row) * ldb + k0 + kc, &Bs[row][kc]);
    }
    __syncthreads();
#pragma unroll
    for (int kk = 0; kk < 2; kk++) {
      bf16x8 af[4], bfr[4];
#pragma unroll
      for (int i = 0; i < 4; i++) af[i]  = *(const bf16x8*)(&As[wr + i * 16 + la][kk * 32 + gq * 8]);
#pragma unroll
      for (int j = 0; j < 4; j++) bfr[j] = *(const bf16x8*)(&Bs[wc + j * 16 + la][kk * 32 + gq * 8]);
#pragma unroll
      for (int i = 0; i < 4; i++)
#pragma unroll
        for (int j = 0; j < 4; j++)
          acc[i][j] = __builtin_amdgcn_mfma_f32_16x16x32_bf16(af[i], bfr[j], acc[i][j], 0, 0, 0);
    }
    __syncthreads();
  }

#pragma unroll
  for (int i = 0; i < 4; i++) {
    int rowb = m0 + wr + i * 16 + gq * 4;
#pragma unroll
    for (int j = 0; j < 4; j++) {
      int col = n0 + wc + j * 16 + la;
      if (col >= N) continue;
      if (mode == 2) {
#pragma unroll
        for (int r = 0; r < 4; r++)
          ((float*)Cv)[(size_t)(rowb + r) * ldc + col] = acc[i][j][r];
      } else if (mode == 4) {
        if (col < DTR) {
#pragma unroll
          for (int r = 0; r < 4; r++)
            ((short*)Cv)[(size_t)(rowb + r) * ldc + col] = f2bs(acc[i][j][r]);
        } else {
          s16x4 pk;
#pragma unroll
          for (int r = 0; r < 4; r++) pk[r] = f2bs(acc[i][j][r]);
          *(s16x4*)((short*)Cv2 + (size_t)(col - DTR) * ldc2 + rowb) = pk;
        }
      } else if (mode == 5) {
        short* base = (col < DI) ? (short*)Cv : (short*)Cv2;
        int c = (col < DI) ? col : col - DI;
        int ld = (col < DI) ? ldc : ldc2;
#pragma unroll
        for (int r = 0; r < 4; r++)
          base[(size_t)(rowb + r) * ld + c] = f2bs(acc[i][j][r]);
      } else if (mode == 6) {
        // softplus + per-ROW bias, row-major bf16 store (col = t is lane-consecutive)
#pragma unroll
        for (int r = 0; r < 4; r++) {
          float v = acc[i][j][r] + bias[rowb + r];
          float e = exp2f(v * 1.44269504f);
          v = (v > 20.f) ? v : 0.69314718f * __log2f(1.f + e);
          ((short*)Cv)[(size_t)(rowb + r) * ldc + col] = f2bs(v);
        }
      } else { // mode 0: plain bf16 token-major
#pragma unroll
        for (int r = 0; r < 4; r++)
          ((short*)Cv)[(size_t)(rowb + r) * ldc + col] = f2bs(acc[i][j][r]);
      }
    }
  }
}

// ---------------------------------------------------------------------------
// depthwise causal conv1d (k=4) + bias + SiLU.  Reads xb[token][DI].
// ---------------------------------------------------------------------------
__global__ __launch_bounds__(256)
void conv_silu(const short* __restrict__ xb, const float* __restrict__ cw,
               const float* __restrict__ cb, short* __restrict__ xs)
{
  const int token = blockIdx.x;
  const int l = token & (L_ - 1);
  const int d0 = threadIdx.x * 8;

  float w[32];
#pragma unroll
  for (int i = 0; i < 8; i++) {
    float4 t = *(const float4*)(cw + (size_t)(d0 + i) * 4);
    w[i * 4 + 0] = t.x; w[i * 4 + 1] = t.y; w[i * 4 + 2] = t.z; w[i * 4 + 3] = t.w;
  }
  float acc[8];
  {
    float4 b0 = *(const float4*)(cb + d0);
    float4 b1 = *(const float4*)(cb + d0 + 4);
    acc[0] = b0.x; acc[1] = b0.y; acc[2] = b0.z; acc[3] = b0.w;
    acc[4] = b1.x; acc[5] = b1.y; acc[6] = b1.z; acc[7] = b1.w;
  }
#pragma unroll
  for (int j = 0; j < 4; j++) {
    int lj = l - 3 + j;
    if (lj >= 0) {
      bf16x8 xv = *(const bf16x8*)(xb + (size_t)(token - 3 + j) * DI + d0);
#pragma unroll
      for (int i = 0; i < 8; i++) acc[i] += w[i * 4 + j] * bf2f(xv[i]);
    }
  }
  union { bf16x8 v; short h[8]; } o;
#pragma unroll
  for (int i = 0; i < 8; i++) {
    float v = acc[i];
    o.h[i] = f2bs(v * sigmoidf_fast(v));
  }
  *(bf16x8*)(xs + (size_t)token * DI + d0) = o.v;
}

// ---------------------------------------------------------------------------
// selective scan, 16 lanes per (b,d) channel (one per state n), fused gating.
//  - dt from dT[d][t], B/C from dbcT[n][t] (contiguous 32B vec loads)
//  - u: lane n loads ONLY u[lv+n][d], then 16 ds_swizzle broadcasts
//  - dA = exp2f(dt * An*log2e)
//  - u*D applied AFTER the reduce (lane n owns step lv+n)
//  - butterfly xor transpose-reduce -> full-wave gate + scatter store
//  - 4-buffer register pipeline, loads issued ~2-3 batches (32-48 steps)
//    ahead to cover ~900-cycle HBM latency on the dT/u/res streams.
// ---------------------------------------------------------------------------
__global__ __launch_bounds__(256, 2)
void scan_kernel(const short* __restrict__ dT, const short* __restrict__ dbcT,
                 const short* __restrict__ xs, short* __restrict__ resy,
                 const float* __restrict__ A_log, const float* __restrict__ Dw,
                 const float* __restrict__ h0)
{
  const int lane = threadIdx.x & 63;
  const int grp = threadIdx.x >> 4, n = threadIdx.x & 15;
  const int ch = blockIdx.x * 16 + grp;          // ch = b*DI + d
  const int b = ch >> 11, d = ch & (DI - 1);
  const bool b3 = (lane & 8) != 0, b2 = (lane & 4) != 0,
             b1 = (lane & 2) != 0, b0 = (lane & 1) != 0;
  const float An2 = -__expf(A_log[d * NST + n]) * 1.44269504f;  // An * log2(e)
  const float Dd = Dw[d];
  float h = h0[(size_t)ch * NST + n];

  const size_t t0 = (size_t)b * L_;
  const short* dRow = dT   + (size_t)d * NTOK + t0;
  const short* bRow = dbcT + (size_t)n * NTOK + t0;
  const short* cRow = bRow + (size_t)NST * NTOK;
  const short* uLn  = xs   + (t0 + n) * DI + d;  // per-lane u row (lane n = step lv+n)
  short*       yCol = resy + (t0 + n) * DI + d;  // res read / y write, per-lane row

  struct Batch { bf16x8 t0v, t1v, B0v, B1v, C0v, C1v; short uo, rr; };

  auto LOADB = [&](int lv, Batch& S) {
    S.t0v = *(const bf16x8*)(dRow + lv);
    S.t1v = *(const bf16x8*)(dRow + lv + 8);
    S.B0v = *(const bf16x8*)(bRow + lv);
    S.B1v = *(const bf16x8*)(bRow + lv + 8);
    S.C0v = *(const bf16x8*)(cRow + lv);
    S.C1v = *(const bf16x8*)(cRow + lv + 8);
    S.uo = uLn[(size_t)lv * DI];                 // u[lv+n][d], one load per lane
    S.rr = yCol[(size_t)lv * DI];
  };

  auto STEP = [&](int lv, const Batch& S) {
    const float uown = bf2f(S.uo);
    // ---- broadcast u[s] to all lanes of the group (VALU/LDS-pipe, no VMEM) ----
    float uf[16];
    uf[0]  = swz_bcast16<0>(uown);   uf[1]  = swz_bcast16<1>(uown);
    uf[2]  = swz_bcast16<2>(uown);   uf[3]  = swz_bcast16<3>(uown);
    uf[4]  = swz_bcast16<4>(uown);   uf[5]  = swz_bcast16<5>(uown);
    uf[6]  = swz_bcast16<6>(uown);   uf[7]  = swz_bcast16<7>(uown);
    uf[8]  = swz_bcast16<8>(uown);   uf[9]  = swz_bcast16<9>(uown);
    uf[10] = swz_bcast16<10>(uown);  uf[11] = swz_bcast16<11>(uown);
    uf[12] = swz_bcast16<12>(uown);  uf[13] = swz_bcast16<13>(uown);
    uf[14] = swz_bcast16<14>(uown);  uf[15] = swz_bcast16<15>(uown);
    // ---- precompute (independent of h) ----
    float dA[16], w[16];
#pragma unroll
    for (int s = 0; s < 16; s++) {
      float dt = bf2f(s < 8 ? S.t0v[s] : S.t1v[s - 8]);
      dA[s] = exp2f(dt * An2);
      w[s]  = dt * uf[s] * bf2f(s < 8 ? S.B0v[s] : S.B1v[s - 8]);
    }
    // ---- serial chain (16 FMAs) + per-state output term ----
    float p[16];
#pragma unroll
    for (int s = 0; s < 16; s++) {
      h = __builtin_fmaf(dA[s], h, w[s]);
      p[s] = h * bf2f(s < 8 ? S.C0v[s] : S.C1v[s - 8]);
    }
    // ---- butterfly transpose-reduce: lane n -> sum over states of p[n] ----
    float q8[8];
#pragma unroll
    for (int i = 0; i < 8; i++) {
      float keep = b3 ? p[i + 8] : p[i];
      float send = b3 ? p[i]     : p[i + 8];
      q8[i] = keep + swz_xor8(send);
    }
    float q4[4];
#pragma unroll
    for (int i = 0; i < 4; i++) {
      float keep = b2 ? q8[i + 4] : q8[i];
      float send = b2 ? q8[i]     : q8[i + 4];
      q4[i] = keep + swz_xor4(send);
    }
    float q2[2];
#pragma unroll
    for (int i = 0; i < 2; i++) {
      float keep = b1 ? q4[i + 2] : q4[i];
      float send = b1 ? q4[i]     : q4[i + 2];
      q2[i] = keep + qperm<0x4E>(send);       // quad_perm [2,3,0,1] = xor 2
    }
    float keep = b0 ? q2[1] : q2[0];
    float send = b0 ? q2[0] : q2[1];
    float ysum = keep + qperm<0xB1>(send);     // quad_perm [1,0,3,2] = xor 1
    // ---- skip term + gate + store (lane n owns step lv+n; uown = u[lv+n]) ----
    ysum = __builtin_fmaf(uown, Dd, ysum);
    float r = bf2f(S.rr);
    float yv = ysum * (r * sigmoidf_fast(r));
    yCol[(size_t)lv * DI] = f2bs(yv);
  };

  Batch s0, s1, s2, s3;
  LOADB(0, s0); LOADB(16, s1); LOADB(32, s2);
  for (int l = 0; l < L_; l += 64) {
    LOADB(l + 48, s3);
    STEP(l, s0);
    if (l + 64 < L_) LOADB(l + 64, s0);
    STEP(l + 16, s1);
    if (l + 80 < L_) LOADB(l + 80, s1);
    STEP(l + 32, s2);
    if (l + 96 < L_) LOADB(l + 96, s2);
    STEP(l + 48, s3);
  }
}

// ---------------------------------------------------------------------------
extern "C" void kernel_launch(void* const* d_in, const int* in_sizes, int n_in,
                              void* d_out, int out_size, void* d_ws, size_t ws_size,
                              hipStream_t stream)
{
  const float* u        = (const float*)d_in[0];
  const float* hiddens  = (const float*)d_in[1];
  const float* in_proj  = (const float*)d_in[2];
  const float* conv_w   = (const float*)d_in[3];
  const float* conv_b   = (const float*)d_in[4];
  const float* x_proj   = (const float*)d_in[5];   // (2048, 96)
  const float* dt_proj  = (const float*)d_in[6];   // (64, 2048)
  const float* dt_bias  = (const float*)d_in[7];
  const float* A_log    = (const float*)d_in[8];
  const float* Dw       = (const float*)d_in[9];
  const float* out_proj = (const float*)d_in[10];
  float* out = (float*)d_out;

  // workspace: ~74 MiB (under the previously proven 78 MiB)
  char* w = (char*)d_ws;
  short* Wt1  = (short*)w;                                 // in_proj^T (4096x1024), 8 MiB
  short* Wt4  = Wt1;                                       // out_proj^T reuses Wt1 after GEMM1
  w += (size_t)4096 * 1024 * 2;
  short* Wxp  = (short*)w; w += (size_t)128  * 2048 * 2;   // x_proj^T, padded to 128 rows
  short* dtw  = (short*)w; w += (size_t)2048 * 64   * 2;   // dt_proj^T  (2048 x 64)
  short* xbuf = (short*)w; w += (size_t)NTOK * DI   * 2;   // x (token-major) -> dT (chan-major)
  short* resy = (short*)w; w += (size_t)NTOK * DI   * 2;   // res (token-major) -> y in-place
  short* dbc  = (short*)w; w += (size_t)NTOK * DTR  * 2;   // dt_rank part, token-major (8192x64)
  short* dbcT = (short*)w; w += (size_t)32   * NTOK * 2;   // B|C transposed (32 x 8192)
  short* ub   = (short*)d_out;                             // u in bf16 (16 MiB, dead after GEMM1)
  short* xs   = (short*)d_out;                             // conv out borrows d_out after GEMM1
  short* dT   = xbuf;                                      // delta^T overlays dead x

  dim3 tb(32, 8);
  cvt_f2b<<<4096, 256, 0, stream>>>(u, ub);                // u -> bf16 (8192x1024)
  transpose_f2b<<<dim3(32, 128), tb, 0, stream>>>(in_proj,  Wt1, 1024, 4096, 4096, 1024);
  transpose_f2b<<<dim3(64, 3),   tb, 0, stream>>>(x_proj,   Wxp, 2048, 96,   96,   2048);
  transpose_f2b<<<dim3(2, 64),   tb, 0, stream>>>(dt_proj,  dtw, 64,   2048, 2048, 64);

  // GEMM1: [x | res] = ub @ in_proj, split into xbuf / resy (token-major, ld=DI)
  gemm_bt<<<dim3(64, 32), 256, 0, stream>>>(ub, Wt1, xbuf, resy, nullptr,
                                            4096, 1024, 1024, 1024, DI, DI, 5);
  // out_proj^T into the now-free Wt1 region (stream-ordered after GEMM1)
  transpose_f2b<<<dim3(64, 32),  tb, 0, stream>>>(out_proj, Wt4, 2048, 1024, 1024, 2048);
  // conv + silu -> xs (token-major, in d_out; ub dead from here)
  conv_silu<<<NTOK, 256, 0, stream>>>(xbuf, conv_w, conv_b, xs);
  // GEMM2: dbc = xs @ x_proj; dt-rank cols token-major, B/C cols transposed to dbcT
  gemm_bt<<<dim3(64, 1), 256, 0, stream>>>(xs, Wxp, dbc, dbcT, nullptr,
                                           96, 2048, 2048, 2048, DTR, NTOK, 4);
  // GEMM3 (swapped operands): dT[d][t] = softplus(dtw[d,:] . dbc[t,:] + bias[d])
  gemm_bt<<<dim3(16, 64), 256, 0, stream>>>(dtw, dbc, dT, nullptr, dt_bias,
                                            NTOK, 64, 64, 64, NTOK, 0, 6);
  // selective scan + gated epilogue: y overwrites res in-place (token-major)
  scan_kernel<<<512, 256, 0, stream>>>(dT, dbcT, xs, resy, A_log, Dw, hiddens);
  // GEMM4: out = y @ out_proj  (8192 x 1024, f32 store)
  gemm_bt<<<dim3(64, 8), 256, 0, stream>>>(resy, Wt4, out, nullptr, nullptr,
                                           1024, 2048, 2048, 2048, 1024, 0, 2);
}

// Round 6
// 617.171 us; speedup vs baseline: 1.5797x; 1.0279x over previous
//
#include <hip/hip_runtime.h>
#include <hip/hip_bf16.h>
#include <cstddef>

#define B_   4
#define L_   2048
#define DM   1024
#define DI   2048
#define NST  16
#define DTR  64        // (1024+15)//16 = 64
#define NBC  96        // DTR + 2*NST
#define NTOK 8192      // B_*L_

using bf16 = __hip_bfloat16;
typedef __attribute__((ext_vector_type(8))) short bf16x8;
typedef __attribute__((ext_vector_type(4))) short s16x4;
typedef __attribute__((ext_vector_type(4))) float f32x4;

__device__ __forceinline__ float bf2f(short s) {
  unsigned u = ((unsigned)(unsigned short)s) << 16;
  float f; __builtin_memcpy(&f, &u, 4); return f;
}
__device__ __forceinline__ short f2bs(float f) {
  __hip_bfloat16 h = __float2bfloat16(f);
  short s; __builtin_memcpy(&s, &h, 2); return s;
}
__device__ __forceinline__ float sigmoidf_fast(float x) {
  return 1.f / (1.f + __expf(-x));
}

// async global->LDS, 16B per lane (dest must be wave-uniform base + lane*16)
#define GLD16(g, l) __builtin_amdgcn_global_load_lds( \
  (const __attribute__((address_space(1))) unsigned int*)(g), \
  (__attribute__((address_space(3))) unsigned int*)(l), 16, 0, 0)

// cross-lane xor shuffles for the 16-state butterfly reduce
__device__ __forceinline__ float swz_xor8(float x) {
  return __builtin_bit_cast(float,
    __builtin_amdgcn_ds_swizzle(__builtin_bit_cast(int, x), 0x201F)); // lane ^= 8
}
__device__ __forceinline__ float swz_xor4(float x) {
  return __builtin_bit_cast(float,
    __builtin_amdgcn_ds_swizzle(__builtin_bit_cast(int, x), 0x101F)); // lane ^= 4
}
template<int CTRL>
__device__ __forceinline__ float qperm(float x) {  // DPP quad_perm, full VALU rate
  return __builtin_bit_cast(float,
    __builtin_amdgcn_update_dpp(0, __builtin_bit_cast(int, x), CTRL, 0xf, 0xf, false));
}
// broadcast lane (group_base | S) to all 16 lanes of the group
template<int S>
__device__ __forceinline__ float swz_bcast16(float x) {
  return __builtin_bit_cast(float,
    __builtin_amdgcn_ds_swizzle(__builtin_bit_cast(int, x), (S << 5) | 0x10));
}

// ---------------------------------------------------------------------------
// prep: one dispatch doing (a) u f32->bf16 convert, (b) in_proj^T,
// (c) x_proj^T, (d) dt_proj^T.  Linear block id -> region.
// out_proj^T is NOT here (it reuses Wt1's space and must run after GEMM1).
// ---------------------------------------------------------------------------
__device__ __forceinline__ void transpose_tile(
    const float* __restrict__ in, short* __restrict__ out,
    int R, int Cc, int lin, int lout, int bx, int by, int tid, short (*t)[33])
{
  const int r0 = bx * 32, c0 = by * 32;
  const int tx = tid & 31, ty = tid >> 5;
#pragma unroll
  for (int i = 0; i < 4; i++) {
    int r = r0 + ty + i * 8;
    int c = c0 + tx;
    short v = 0;
    if (r < R && c < Cc) v = f2bs(in[(size_t)r * lin + c]);
    t[ty + i * 8][tx] = v;
  }
  __syncthreads();
#pragma unroll
  for (int i = 0; i < 4; i++) {
    int c = c0 + ty + i * 8;
    int r = r0 + tx;
    if (c < Cc && r < lout) out[(size_t)c * lout + r] = t[tx][ty + i * 8];
  }
}

__global__ __launch_bounds__(256)
void prep(const float* __restrict__ u, short* __restrict__ ub,
          const float* __restrict__ in_proj, short* __restrict__ Wt1,
          const float* __restrict__ x_proj, short* __restrict__ Wxp,
          const float* __restrict__ dt_proj, short* __restrict__ dtw)
{
  __shared__ short t[32][33];
  int id = blockIdx.x;
  const int tid = threadIdx.x;
  if (id < 4096) {                       // u convert: 4096 blocks x 256 thr x 8
    const size_t i = ((size_t)id * 256 + tid) * 8;
    float4 a0 = *(const float4*)(u + i);
    float4 a1 = *(const float4*)(u + i + 4);
    union { bf16x8 v; short h[8]; } o;
    o.h[0] = f2bs(a0.x); o.h[1] = f2bs(a0.y); o.h[2] = f2bs(a0.z); o.h[3] = f2bs(a0.w);
    o.h[4] = f2bs(a1.x); o.h[5] = f2bs(a1.y); o.h[6] = f2bs(a1.z); o.h[7] = f2bs(a1.w);
    *(bf16x8*)(ub + i) = o.v;
    return;
  }
  id -= 4096;
  if (id < 4096) {                       // in_proj^T: grid (32,128)
    transpose_tile(in_proj, Wt1, 1024, 4096, 4096, 1024, id & 31, id >> 5, tid, t);
    return;
  }
  id -= 4096;
  if (id < 192) {                        // x_proj^T: grid (64,3)
    transpose_tile(x_proj, Wxp, 2048, 96, 96, 2048, id % 64, id / 64, tid, t);
    return;
  }
  id -= 192;                             // dt_proj^T: grid (2,64)
  transpose_tile(dt_proj, dtw, 64, 2048, 2048, 64, id & 1, id >> 1, tid, t);
}

// ---------------------------------------------------------------------------
// transpose f32 in -> bf16 out (standalone, used for out_proj after GEMM1)
// ---------------------------------------------------------------------------
__global__ __launch_bounds__(256)
void transpose_f2b(const float* __restrict__ in, short* __restrict__ out,
                   int R, int Cc, int lin, int lout)
{
  __shared__ short t[32][33];
  transpose_tile(in, out, R, Cc, lin, lout, blockIdx.x, blockIdx.y,
                 threadIdx.x + threadIdx.y * 32, t);
}

// ---------------------------------------------------------------------------
// bf16 MFMA GEMM, C[M x N] = A[M x K] * Bt[N x K]^T.  128x128 tile, BK=64,
// 4 waves each 64x64 (4x4 of 16x16x32 MFMA).  global_load_lds (16B) staging,
// linear LDS dest with XOR-swizzled SOURCE col (T2 per rule #21): physical
// [row][kc] holds logical [row][kc ^ ((row&7)<<3)]; reads apply the same XOR.
// Breaks the [128][64]=128B-row 16-way bank conflict on ds_read_b128.
// A/B tile rows are read UNGUARDED: buffers allocated with >= ceil128 rows.
// XCD-aware bijective block swizzle (requires gridDim.x*gridDim.y % 8 == 0).
// mode 2: f32 token-major store.
// mode 4: col<DTR -> bf16 token-major to Cv (ldc); col>=DTR -> bf16 transposed to Cv2 (ldc2)
// mode 5: col<DI  -> bf16 token-major to Cv (ldc); col>=DI  -> token-major to Cv2 (ldc2)
// mode 6: softplus(v + bias[ROW]) -> bf16 row-major store (ldc)  [GEMM3 swapped form]
// ---------------------------------------------------------------------------
__global__ __launch_bounds__(256)
void gemm_bt(const short* __restrict__ A, const short* __restrict__ Bt,
             void* __restrict__ Cv, void* __restrict__ Cv2, const float* __restrict__ bias,
             int N, int K, int lda, int ldb, int ldc, int ldc2, int mode)
{
  __shared__ short As[128][64];
  __shared__ short Bs[128][64];
  // ---- XCD swizzle: dispatch i -> XCD i%8; give XCD k contiguous work chunk ----
  const int gx = gridDim.x;
  const int nwg = gx * gridDim.y;
  const int lid = blockIdx.x + gx * blockIdx.y;
  const int cpx = nwg >> 3;                       // nwg % 8 == 0 for all call sites
  const int swz = (lid & 7) * cpx + (lid >> 3);
  const int m0 = (swz % gx) * 128;
  const int n0 = (swz / gx) * 128;
  const int tid  = threadIdx.x;
  const int wave = tid >> 6, lane = tid & 63;
  const int wr = (wave >> 1) * 64, wc = (wave & 1) * 64;
  const int la = lane & 15, gq = lane >> 4;
  const int rs = (la & 7) << 3;                   // read-side XOR (row&7 == la&7)
  f32x4 acc[4][4] = {};

  for (int k0 = 0; k0 < K; k0 += 64) {
#pragma unroll
    for (int i = 0; i < 4; i++) {
      int idx = tid + i * 256;                    // 0..1023
      int row = idx >> 3, kc = (idx & 7) * 8;     // linear LDS dest: addr = idx*16B
      int kcs = kc ^ ((row & 7) << 3);            // pre-swizzled global source col
      GLD16(A  + (size_t)(m0 + row) * lda + k0 + kcs, &As[row][kc]);
      GLD16(Bt + (size_t)(n0 + row) * ldb + k0 + kcs, &Bs[row][kc]);
    }
    __syncthreads();
#pragma unroll
    for (int kk = 0; kk < 2; kk++) {
      const int cl = (kk * 32 + gq * 8) ^ rs;     // swizzled read col
      bf16x8 af[4], bfr[4];
#pragma unroll
      for (int i = 0; i < 4; i++) af[i]  = *(const bf16x8*)(&As[wr + i * 16 + la][cl]);
#pragma unroll
      for (int j = 0; j < 4; j++) bfr[j] = *(const bf16x8*)(&Bs[wc + j * 16 + la][cl]);
#pragma unroll
      for (int i = 0; i < 4; i++)
#pragma unroll
        for (int j = 0; j < 4; j++)
          acc[i][j] = __builtin_amdgcn_mfma_f32_16x16x32_bf16(af[i], bfr[j], acc[i][j], 0, 0, 0);
    }
    __syncthreads();
  }

#pragma unroll
  for (int i = 0; i < 4; i++) {
    int rowb = m0 + wr + i * 16 + gq * 4;
#pragma unroll
    for (int j = 0; j < 4; j++) {
      int col = n0 + wc + j * 16 + la;
      if (col >= N) continue;
      if (mode == 2) {
#pragma unroll
        for (int r = 0; r < 4; r++)
          ((float*)Cv)[(size_t)(rowb + r) * ldc + col] = acc[i][j][r];
      } else if (mode == 4) {
        if (col < DTR) {
#pragma unroll
          for (int r = 0; r < 4; r++)
            ((short*)Cv)[(size_t)(rowb + r) * ldc + col] = f2bs(acc[i][j][r]);
        } else {
          s16x4 pk;
#pragma unroll
          for (int r = 0; r < 4; r++) pk[r] = f2bs(acc[i][j][r]);
          *(s16x4*)((short*)Cv2 + (size_t)(col - DTR) * ldc2 + rowb) = pk;
        }
      } else if (mode == 5) {
        short* base = (col < DI) ? (short*)Cv : (short*)Cv2;
        int c = (col < DI) ? col : col - DI;
        int ld = (col < DI) ? ldc : ldc2;
#pragma unroll
        for (int r = 0; r < 4; r++)
          base[(size_t)(rowb + r) * ld + c] = f2bs(acc[i][j][r]);
      } else if (mode == 6) {
        // softplus + per-ROW bias, row-major bf16 store (col = t is lane-consecutive)
#pragma unroll
        for (int r = 0; r < 4; r++) {
          float v = acc[i][j][r] + bias[rowb + r];
          float e = exp2f(v * 1.44269504f);
          v = (v > 20.f) ? v : 0.69314718f * __log2f(1.f + e);
          ((short*)Cv)[(size_t)(rowb + r) * ldc + col] = f2bs(v);
        }
      } else { // mode 0: plain bf16 token-major
#pragma unroll
        for (int r = 0; r < 4; r++)
          ((short*)Cv)[(size_t)(rowb + r) * ldc + col] = f2bs(acc[i][j][r]);
      }
    }
  }
}

// ---------------------------------------------------------------------------
// depthwise causal conv1d (k=4) + bias + SiLU.  Reads xb[token][DI].
// ---------------------------------------------------------------------------
__global__ __launch_bounds__(256)
void conv_silu(const short* __restrict__ xb, const float* __restrict__ cw,
               const float* __restrict__ cb, short* __restrict__ xs)
{
  const int token = blockIdx.x;
  const int l = token & (L_ - 1);
  const int d0 = threadIdx.x * 8;

  float w[32];
#pragma unroll
  for (int i = 0; i < 8; i++) {
    float4 t = *(const float4*)(cw + (size_t)(d0 + i) * 4);
    w[i * 4 + 0] = t.x; w[i * 4 + 1] = t.y; w[i * 4 + 2] = t.z; w[i * 4 + 3] = t.w;
  }
  float acc[8];
  {
    float4 b0 = *(const float4*)(cb + d0);
    float4 b1 = *(const float4*)(cb + d0 + 4);
    acc[0] = b0.x; acc[1] = b0.y; acc[2] = b0.z; acc[3] = b0.w;
    acc[4] = b1.x; acc[5] = b1.y; acc[6] = b1.z; acc[7] = b1.w;
  }
#pragma unroll
  for (int j = 0; j < 4; j++) {
    int lj = l - 3 + j;
    if (lj >= 0) {
      bf16x8 xv = *(const bf16x8*)(xb + (size_t)(token - 3 + j) * DI + d0);
#pragma unroll
      for (int i = 0; i < 8; i++) acc[i] += w[i * 4 + j] * bf2f(xv[i]);
    }
  }
  union { bf16x8 v; short h[8]; } o;
#pragma unroll
  for (int i = 0; i < 8; i++) {
    float v = acc[i];
    o.h[i] = f2bs(v * sigmoidf_fast(v));
  }
  *(bf16x8*)(xs + (size_t)token * DI + d0) = o.v;
}

// ---------------------------------------------------------------------------
// selective scan, 16 lanes per (b,d) channel (one per state n), fused gating.
// R4-proven structure (222 us, 48 VGPR, no scratch): 2-deep ping-pong —
// deeper forced pipelining spills (R5: 84 VGPR, +8MB scratch writes, slower).
//  - dt from dT[d][t], B/C from dbcT[n][t] (contiguous 32B vec loads)
//  - u: lane n loads ONLY u[lv+n][d], then 16 ds_swizzle broadcasts
//  - dA = exp2f(dt * An*log2e)
//  - u*D applied AFTER the reduce (lane n owns step lv+n)
//  - butterfly xor transpose-reduce -> full-wave gate + scatter store
// ---------------------------------------------------------------------------
__global__ __launch_bounds__(256, 2)
void scan_kernel(const short* __restrict__ dT, const short* __restrict__ dbcT,
                 const short* __restrict__ xs, short* __restrict__ resy,
                 const float* __restrict__ A_log, const float* __restrict__ Dw,
                 const float* __restrict__ h0)
{
  const int lane = threadIdx.x & 63;
  const int grp = threadIdx.x >> 4, n = threadIdx.x & 15;
  const int ch = blockIdx.x * 16 + grp;          // ch = b*DI + d
  const int b = ch >> 11, d = ch & (DI - 1);
  const bool b3 = (lane & 8) != 0, b2 = (lane & 4) != 0,
             b1 = (lane & 2) != 0, b0 = (lane & 1) != 0;
  const float An2 = -__expf(A_log[d * NST + n]) * 1.44269504f;  // An * log2(e)
  const float Dd = Dw[d];
  float h = h0[(size_t)ch * NST + n];

  const size_t t0 = (size_t)b * L_;
  const short* dRow = dT   + (size_t)d * NTOK + t0;
  const short* bRow = dbcT + (size_t)n * NTOK + t0;
  const short* cRow = bRow + (size_t)NST * NTOK;
  const short* uLn  = xs   + (t0 + n) * DI + d;  // per-lane u row (lane n = step lv+n)
  short*       yCol = resy + (t0 + n) * DI + d;  // res read / y write, per-lane row

  auto LOADB = [&](int lv, bf16x8& t0v, bf16x8& t1v, bf16x8& B0v, bf16x8& B1v,
                   bf16x8& C0v, bf16x8& C1v, short& uo, short& rr) {
    t0v = *(const bf16x8*)(dRow + lv);
    t1v = *(const bf16x8*)(dRow + lv + 8);
    B0v = *(const bf16x8*)(bRow + lv);
    B1v = *(const bf16x8*)(bRow + lv + 8);
    C0v = *(const bf16x8*)(cRow + lv);
    C1v = *(const bf16x8*)(cRow + lv + 8);
    uo = uLn[(size_t)lv * DI];                   // u[lv+n][d], one load per lane
    rr = yCol[(size_t)lv * DI];
  };

  auto STEP = [&](int lv, bf16x8 t0v, bf16x8 t1v, bf16x8 B0v, bf16x8 B1v,
                  bf16x8 C0v, bf16x8 C1v, short uo, short rr) {
    const float uown = bf2f(uo);
    // ---- broadcast u[s] to all lanes of the group (LDS-pipe, no VMEM) ----
    float uf[16];
    uf[0]  = swz_bcast16<0>(uown);   uf[1]  = swz_bcast16<1>(uown);
    uf[2]  = swz_bcast16<2>(uown);   uf[3]  = swz_bcast16<3>(uown);
    uf[4]  = swz_bcast16<4>(uown);   uf[5]  = swz_bcast16<5>(uown);
    uf[6]  = swz_bcast16<6>(uown);   uf[7]  = swz_bcast16<7>(uown);
    uf[8]  = swz_bcast16<8>(uown);   uf[9]  = swz_bcast16<9>(uown);
    uf[10] = swz_bcast16<10>(uown);  uf[11] = swz_bcast16<11>(uown);
    uf[12] = swz_bcast16<12>(uown);  uf[13] = swz_bcast16<13>(uown);
    uf[14] = swz_bcast16<14>(uown);  uf[15] = swz_bcast16<15>(uown);
    // ---- precompute (independent of h) ----
    float dA[16], w[16];
#pragma unroll
    for (int s = 0; s < 16; s++) {
      float dt = bf2f(s < 8 ? t0v[s] : t1v[s - 8]);
      dA[s] = exp2f(dt * An2);
      w[s]  = dt * uf[s] * bf2f(s < 8 ? B0v[s] : B1v[s - 8]);
    }
    // ---- serial chain (16 FMAs) + per-state output term ----
    float p[16];
#pragma unroll
    for (int s = 0; s < 16; s++) {
      h = __builtin_fmaf(dA[s], h, w[s]);
      p[s] = h * bf2f(s < 8 ? C0v[s] : C1v[s - 8]);
    }
    // ---- butterfly transpose-reduce: lane n -> sum over states of p[n] ----
    float q8[8];
#pragma unroll
    for (int i = 0; i < 8; i++) {
      float keep = b3 ? p[i + 8] : p[i];
      float send = b3 ? p[i]     : p[i + 8];
      q8[i] = keep + swz_xor8(send);
    }
    float q4[4];
#pragma unroll
    for (int i = 0; i < 4; i++) {
      float keep = b2 ? q8[i + 4] : q8[i];
      float send = b2 ? q8[i]     : q8[i + 4];
      q4[i] = keep + swz_xor4(send);
    }
    float q2[2];
#pragma unroll
    for (int i = 0; i < 2; i++) {
      float keep = b1 ? q4[i + 2] : q4[i];
      float send = b1 ? q4[i]     : q4[i + 2];
      q2[i] = keep + qperm<0x4E>(send);       // quad_perm [2,3,0,1] = xor 2
    }
    float keep = b0 ? q2[1] : q2[0];
    float send = b0 ? q2[0] : q2[1];
    float ysum = keep + qperm<0xB1>(send);     // quad_perm [1,0,3,2] = xor 1
    // ---- skip term + gate + store (lane n owns step lv+n; uown = u[lv+n]) ----
    ysum = __builtin_fmaf(uown, Dd, ysum);
    float r = bf2f(rr);
    float yv = ysum * (r * sigmoidf_fast(r));
    yCol[(size_t)lv * DI] = f2bs(yv);
  };

  bf16x8 a0, a1, a2, a3, a4, a5; short ua, ra;
  bf16x8 c0, c1, c2, c3, c4, c5; short ub, rb;
  LOADB(0, a0, a1, a2, a3, a4, a5, ua, ra);
  for (int l = 0; l < L_; l += 32) {
    LOADB(l + 16, c0, c1, c2, c3, c4, c5, ub, rb);
    STEP(l, a0, a1, a2, a3, a4, a5, ua, ra);
    if (l + 32 < L_) LOADB(l + 32, a0, a1, a2, a3, a4, a5, ua, ra);
    STEP(l + 16, c0, c1, c2, c3, c4, c5, ub, rb);
  }
}

// ---------------------------------------------------------------------------
extern "C" void kernel_launch(void* const* d_in, const int* in_sizes, int n_in,
                              void* d_out, int out_size, void* d_ws, size_t ws_size,
                              hipStream_t stream)
{
  const float* u        = (const float*)d_in[0];
  const float* hiddens  = (const float*)d_in[1];
  const float* in_proj  = (const float*)d_in[2];
  const float* conv_w   = (const float*)d_in[3];
  const float* conv_b   = (const float*)d_in[4];
  const float* x_proj   = (const float*)d_in[5];   // (2048, 96)
  const float* dt_proj  = (const float*)d_in[6];   // (64, 2048)
  const float* dt_bias  = (const float*)d_in[7];
  const float* A_log    = (const float*)d_in[8];
  const float* Dw       = (const float*)d_in[9];
  const float* out_proj = (const float*)d_in[10];
  float* out = (float*)d_out;

  // workspace: ~74 MiB (under the previously proven 78 MiB)
  char* w = (char*)d_ws;
  short* Wt1  = (short*)w;                                 // in_proj^T (4096x1024), 8 MiB
  short* Wt4  = Wt1;                                       // out_proj^T reuses Wt1 after GEMM1
  w += (size_t)4096 * 1024 * 2;
  short* Wxp  = (short*)w; w += (size_t)128  * 2048 * 2;   // x_proj^T, padded to 128 rows
  short* dtw  = (short*)w; w += (size_t)2048 * 64   * 2;   // dt_proj^T  (2048 x 64)
  short* xbuf = (short*)w; w += (size_t)NTOK * DI   * 2;   // x (token-major) -> dT (chan-major)
  short* resy = (short*)w; w += (size_t)NTOK * DI   * 2;   // res (token-major) -> y in-place
  short* dbc  = (short*)w; w += (size_t)NTOK * DTR  * 2;   // dt_rank part, token-major (8192x64)
  short* dbcT = (short*)w; w += (size_t)32   * NTOK * 2;   // B|C transposed (32 x 8192)
  short* ub   = (short*)d_out;                             // u in bf16 (16 MiB, dead after GEMM1)
  short* xs   = (short*)d_out;                             // conv out borrows d_out after GEMM1
  short* dT   = xbuf;                                      // delta^T overlays dead x

  // prep: u->bf16 + in_proj^T + x_proj^T + dt_proj^T in ONE dispatch
  prep<<<4096 + 4096 + 192 + 128, 256, 0, stream>>>(u, ub, in_proj, Wt1,
                                                    x_proj, Wxp, dt_proj, dtw);

  // GEMM1: [x | res] = ub @ in_proj, split into xbuf / resy (token-major, ld=DI)
  gemm_bt<<<dim3(64, 32), 256, 0, stream>>>(ub, Wt1, xbuf, resy, nullptr,
                                            4096, 1024, 1024, 1024, DI, DI, 5);
  // out_proj^T into the now-free Wt1 region (stream-ordered after GEMM1)
  transpose_f2b<<<dim3(64, 32), dim3(32, 8), 0, stream>>>(out_proj, Wt4, 2048, 1024, 1024, 2048);
  // conv + silu -> xs (token-major, in d_out; ub dead from here)
  conv_silu<<<NTOK, 256, 0, stream>>>(xbuf, conv_w, conv_b, xs);
  // GEMM2: dbc = xs @ x_proj; dt-rank cols token-major, B/C cols transposed to dbcT
  gemm_bt<<<dim3(64, 1), 256, 0, stream>>>(xs, Wxp, dbc, dbcT, nullptr,
                                           96, 2048, 2048, 2048, DTR, NTOK, 4);
  // GEMM3 (swapped operands): dT[d][t] = softplus(dtw[d,:] . dbc[t,:] + bias[d])
  gemm_bt<<<dim3(16, 64), 256, 0, stream>>>(dtw, dbc, dT, nullptr, dt_bias,
                                            NTOK, 64, 64, 64, NTOK, 0, 6);
  // selective scan + gated epilogue: y overwrites res in-place (token-major)
  scan_kernel<<<512, 256, 0, stream>>>(dT, dbcT, xs, resy, A_log, Dw, hiddens);
  // GEMM4: out = y @ out_proj  (8192 x 1024, f32 store)
  gemm_bt<<<dim3(64, 8), 256, 0, stream>>>(resy, Wt4, out, nullptr, nullptr,
                                           1024, 2048, 2048, 2048, 1024, 0, 2);
}

// Round 7
// 597.503 us; speedup vs baseline: 1.6317x; 1.0329x over previous
//
#include <hip/hip_runtime.h>
#include <hip/hip_bf16.h>
#include <cstddef>

#define B_   4
#define L_   2048
#define DM   1024
#define DI   2048
#define NST  16
#define DTR  64        // (1024+15)//16 = 64
#define NBC  96        // DTR + 2*NST
#define NTOK 8192      // B_*L_

using bf16 = __hip_bfloat16;
typedef __attribute__((ext_vector_type(8))) short bf16x8;
typedef __attribute__((ext_vector_type(4))) short s16x4;
typedef __attribute__((ext_vector_type(4))) float f32x4;

__device__ __forceinline__ float bf2f(short s) {
  unsigned u = ((unsigned)(unsigned short)s) << 16;
  float f; __builtin_memcpy(&f, &u, 4); return f;
}
__device__ __forceinline__ short f2bs(float f) {
  __hip_bfloat16 h = __float2bfloat16(f);
  short s; __builtin_memcpy(&s, &h, 2); return s;
}
__device__ __forceinline__ float sigmoidf_fast(float x) {
  return 1.f / (1.f + __expf(-x));
}

// async global->LDS, 16B per lane (dest must be wave-uniform base + lane*16)
#define GLD16(g, l) __builtin_amdgcn_global_load_lds( \
  (const __attribute__((address_space(1))) unsigned int*)(g), \
  (__attribute__((address_space(3))) unsigned int*)(l), 16, 0, 0)

// cross-lane xor shuffles for the 16-state butterfly reduce
__device__ __forceinline__ float swz_xor8(float x) {
  return __builtin_bit_cast(float,
    __builtin_amdgcn_ds_swizzle(__builtin_bit_cast(int, x), 0x201F)); // lane ^= 8
}
__device__ __forceinline__ float swz_xor4(float x) {
  return __builtin_bit_cast(float,
    __builtin_amdgcn_ds_swizzle(__builtin_bit_cast(int, x), 0x101F)); // lane ^= 4
}
template<int CTRL>
__device__ __forceinline__ float qperm(float x) {  // DPP quad_perm, full VALU rate
  return __builtin_bit_cast(float,
    __builtin_amdgcn_update_dpp(0, __builtin_bit_cast(int, x), CTRL, 0xf, 0xf, false));
}
// broadcast lane (group_base | S) to all 16 lanes of the group
template<int S>
__device__ __forceinline__ float swz_bcast16(float x) {
  return __builtin_bit_cast(float,
    __builtin_amdgcn_ds_swizzle(__builtin_bit_cast(int, x), (S << 5) | 0x10));
}

// ---------------------------------------------------------------------------
// shared transpose tile helper (f32 -> bf16, zero-pad)
// ---------------------------------------------------------------------------
__device__ __forceinline__ void transpose_tile(
    const float* __restrict__ in, short* __restrict__ out,
    int R, int Cc, int lin, int lout, int bx, int by, int tid, short (*t)[33])
{
  const int r0 = bx * 32, c0 = by * 32;
  const int tx = tid & 31, ty = tid >> 5;
#pragma unroll
  for (int i = 0; i < 4; i++) {
    int r = r0 + ty + i * 8;
    int c = c0 + tx;
    short v = 0;
    if (r < R && c < Cc) v = f2bs(in[(size_t)r * lin + c]);
    t[ty + i * 8][tx] = v;
  }
  __syncthreads();
#pragma unroll
  for (int i = 0; i < 4; i++) {
    int c = c0 + ty + i * 8;
    int r = r0 + tx;
    if (c < Cc && r < lout) out[(size_t)c * lout + r] = t[tx][ty + i * 8];
  }
}

// ---------------------------------------------------------------------------
// prep: one dispatch doing (a) u f32->bf16 convert, (b) in_proj^T,
// (c) x_proj^T, (d) dt_proj^T.  Linear block id -> region.
// out_proj^T is NOT here (it reuses Wt1's space; it rides in conv_silu).
// ---------------------------------------------------------------------------
__global__ __launch_bounds__(256)
void prep(const float* __restrict__ u, short* __restrict__ ub,
          const float* __restrict__ in_proj, short* __restrict__ Wt1,
          const float* __restrict__ x_proj, short* __restrict__ Wxp,
          const float* __restrict__ dt_proj, short* __restrict__ dtw)
{
  __shared__ short t[32][33];
  int id = blockIdx.x;
  const int tid = threadIdx.x;
  if (id < 4096) {                       // u convert: 4096 blocks x 256 thr x 8
    const size_t i = ((size_t)id * 256 + tid) * 8;
    float4 a0 = *(const float4*)(u + i);
    float4 a1 = *(const float4*)(u + i + 4);
    union { bf16x8 v; short h[8]; } o;
    o.h[0] = f2bs(a0.x); o.h[1] = f2bs(a0.y); o.h[2] = f2bs(a0.z); o.h[3] = f2bs(a0.w);
    o.h[4] = f2bs(a1.x); o.h[5] = f2bs(a1.y); o.h[6] = f2bs(a1.z); o.h[7] = f2bs(a1.w);
    *(bf16x8*)(ub + i) = o.v;
    return;
  }
  id -= 4096;
  if (id < 4096) {                       // in_proj^T: grid (32,128)
    transpose_tile(in_proj, Wt1, 1024, 4096, 4096, 1024, id & 31, id >> 5, tid, t);
    return;
  }
  id -= 4096;
  if (id < 192) {                        // x_proj^T: grid (64,3)
    transpose_tile(x_proj, Wxp, 2048, 96, 96, 2048, id % 64, id / 64, tid, t);
    return;
  }
  id -= 192;                             // dt_proj^T: grid (2,64)
  transpose_tile(dt_proj, dtw, 64, 2048, 2048, 64, id & 1, id >> 1, tid, t);
}

// ---------------------------------------------------------------------------
// bf16 MFMA GEMM, C[M x N] = A[M x K] * Bt[N x K]^T.  128x128 tile, BK=64,
// 4 waves each 64x64 (4x4 of 16x16x32 MFMA).  global_load_lds (16B) staging,
// linear LDS dest with XOR-swizzled SOURCE col (T2 per rule #21).
// Block mapping: XCD chunk (bijective, i%8 -> XCD) THEN group-M swizzle
// (GM=8: mt fastest within 8 m-tiles, then nt).  Concurrent window per XCD
// = 8 A-panels (2 MB, L2-resident across the whole chunk) + streaming B.
// Fixes the m-fastest A-restream (~512 MB -> ~80 MB HBM on GEMM1).
// Requires nwg % 8 == 0 and gx % 8 == 0 (all call sites).
// mode 2: f32 token-major store.
// mode 4: col<DTR -> bf16 token-major to Cv (ldc); col>=DTR -> bf16 transposed to Cv2 (ldc2)
// mode 5: col<DI  -> bf16 token-major to Cv (ldc); col>=DI  -> token-major to Cv2 (ldc2)
// mode 6: softplus(v + bias[ROW]) -> bf16 row-major store (ldc)  [GEMM3 swapped form]
// ---------------------------------------------------------------------------
__global__ __launch_bounds__(256)
void gemm_bt(const short* __restrict__ A, const short* __restrict__ Bt,
             void* __restrict__ Cv, void* __restrict__ Cv2, const float* __restrict__ bias,
             int N, int K, int lda, int ldb, int ldc, int ldc2, int mode)
{
  __shared__ short As[128][64];
  __shared__ short Bs[128][64];
  // ---- XCD chunk + group-M swizzle ----
  const int gx = gridDim.x, gy = gridDim.y;
  const int nwg = gx * gy;
  const int lid = blockIdx.x + gx * blockIdx.y;
  const int cpx = nwg >> 3;                       // nwg % 8 == 0 for all call sites
  const int swz = (lid & 7) * cpx + (lid >> 3);   // XCD k owns swz in [k*cpx,(k+1)*cpx)
  const int nig = gy << 3;                        // tiles per m-group = GM(8) * gy
  const int grp_ = swz / nig;
  const int ing = swz - grp_ * nig;
  const int m0 = (grp_ * 8 + (ing & 7)) * 128;    // mt fastest within group of 8
  const int n0 = (ing >> 3) * 128;
  const int tid  = threadIdx.x;
  const int wave = tid >> 6, lane = tid & 63;
  const int wr = (wave >> 1) * 64, wc = (wave & 1) * 64;
  const int la = lane & 15, gq = lane >> 4;
  const int rs = (la & 7) << 3;                   // read-side XOR (row&7 == la&7)
  f32x4 acc[4][4] = {};

  for (int k0 = 0; k0 < K; k0 += 64) {
#pragma unroll
    for (int i = 0; i < 4; i++) {
      int idx = tid + i * 256;                    // 0..1023
      int row = idx >> 3, kc = (idx & 7) * 8;     // linear LDS dest: addr = idx*16B
      int kcs = kc ^ ((row & 7) << 3);            // pre-swizzled global source col
      GLD16(A  + (size_t)(m0 + row) * lda + k0 + kcs, &As[row][kc]);
      GLD16(Bt + (size_t)(n0 + row) * ldb + k0 + kcs, &Bs[row][kc]);
    }
    __syncthreads();
#pragma unroll
    for (int kk = 0; kk < 2; kk++) {
      const int cl = (kk * 32 + gq * 8) ^ rs;     // swizzled read col
      bf16x8 af[4], bfr[4];
#pragma unroll
      for (int i = 0; i < 4; i++) af[i]  = *(const bf16x8*)(&As[wr + i * 16 + la][cl]);
#pragma unroll
      for (int j = 0; j < 4; j++) bfr[j] = *(const bf16x8*)(&Bs[wc + j * 16 + la][cl]);
#pragma unroll
      for (int i = 0; i < 4; i++)
#pragma unroll
        for (int j = 0; j < 4; j++)
          acc[i][j] = __builtin_amdgcn_mfma_f32_16x16x32_bf16(af[i], bfr[j], acc[i][j], 0, 0, 0);
    }
    __syncthreads();
  }

#pragma unroll
  for (int i = 0; i < 4; i++) {
    int rowb = m0 + wr + i * 16 + gq * 4;
#pragma unroll
    for (int j = 0; j < 4; j++) {
      int col = n0 + wc + j * 16 + la;
      if (col >= N) continue;
      if (mode == 2) {
#pragma unroll
        for (int r = 0; r < 4; r++)
          ((float*)Cv)[(size_t)(rowb + r) * ldc + col] = acc[i][j][r];
      } else if (mode == 4) {
        if (col < DTR) {
#pragma unroll
          for (int r = 0; r < 4; r++)
            ((short*)Cv)[(size_t)(rowb + r) * ldc + col] = f2bs(acc[i][j][r]);
        } else {
          s16x4 pk;
#pragma unroll
          for (int r = 0; r < 4; r++) pk[r] = f2bs(acc[i][j][r]);
          *(s16x4*)((short*)Cv2 + (size_t)(col - DTR) * ldc2 + rowb) = pk;
        }
      } else if (mode == 5) {
        short* base = (col < DI) ? (short*)Cv : (short*)Cv2;
        int c = (col < DI) ? col : col - DI;
        int ld = (col < DI) ? ldc : ldc2;
#pragma unroll
        for (int r = 0; r < 4; r++)
          base[(size_t)(rowb + r) * ld + c] = f2bs(acc[i][j][r]);
      } else if (mode == 6) {
        // softplus + per-ROW bias, row-major bf16 store (col = t is lane-consecutive)
#pragma unroll
        for (int r = 0; r < 4; r++) {
          float v = acc[i][j][r] + bias[rowb + r];
          float e = exp2f(v * 1.44269504f);
          v = (v > 20.f) ? v : 0.69314718f * __log2f(1.f + e);
          ((short*)Cv)[(size_t)(rowb + r) * ldc + col] = f2bs(v);
        }
      } else { // mode 0: plain bf16 token-major
#pragma unroll
        for (int r = 0; r < 4; r++)
          ((short*)Cv)[(size_t)(rowb + r) * ldc + col] = f2bs(acc[i][j][r]);
      }
    }
  }
}

// ---------------------------------------------------------------------------
// depthwise causal conv1d (k=4) + bias + SiLU (blocks < NTOK), plus
// out_proj^T transpose riding on blocks >= NTOK (out_proj reuses Wt1's
// space, so this must be dispatched after GEMM1 -- it is).
// ---------------------------------------------------------------------------
__global__ __launch_bounds__(256)
void conv_silu(const short* __restrict__ xb, const float* __restrict__ cw,
               const float* __restrict__ cb, short* __restrict__ xs,
               const float* __restrict__ op, short* __restrict__ Wt4)
{
  __shared__ short t[32][33];
  const int blk = blockIdx.x;
  if (blk >= NTOK) {                     // out_proj^T: 2048 blocks, grid (64,32)
    const int id2 = blk - NTOK;
    transpose_tile(op, Wt4, 2048, 1024, 1024, 2048, id2 & 63, id2 >> 6, threadIdx.x, t);
    return;
  }
  const int token = blk;
  const int l = token & (L_ - 1);
  const int d0 = threadIdx.x * 8;

  float w[32];
#pragma unroll
  for (int i = 0; i < 8; i++) {
    float4 tw = *(const float4*)(cw + (size_t)(d0 + i) * 4);
    w[i * 4 + 0] = tw.x; w[i * 4 + 1] = tw.y; w[i * 4 + 2] = tw.z; w[i * 4 + 3] = tw.w;
  }
  float acc[8];
  {
    float4 b0 = *(const float4*)(cb + d0);
    float4 b1 = *(const float4*)(cb + d0 + 4);
    acc[0] = b0.x; acc[1] = b0.y; acc[2] = b0.z; acc[3] = b0.w;
    acc[4] = b1.x; acc[5] = b1.y; acc[6] = b1.z; acc[7] = b1.w;
  }
#pragma unroll
  for (int j = 0; j < 4; j++) {
    int lj = l - 3 + j;
    if (lj >= 0) {
      bf16x8 xv = *(const bf16x8*)(xb + (size_t)(token - 3 + j) * DI + d0);
#pragma unroll
      for (int i = 0; i < 8; i++) acc[i] += w[i * 4 + j] * bf2f(xv[i]);
    }
  }
  union { bf16x8 v; short h[8]; } o;
#pragma unroll
  for (int i = 0; i < 8; i++) {
    float v = acc[i];
    o.h[i] = f2bs(v * sigmoidf_fast(v));
  }
  *(bf16x8*)(xs + (size_t)token * DI + d0) = o.v;
}

// ---------------------------------------------------------------------------
// selective scan, 16 lanes per (b,d) channel (one per state n), fused gating.
// R4-proven structure (222 us, 48 VGPR, no scratch): 2-deep ping-pong —
// deeper forced pipelining spills (R5: 84 VGPR, +8MB scratch writes, slower).
// ---------------------------------------------------------------------------
__global__ __launch_bounds__(256, 2)
void scan_kernel(const short* __restrict__ dT, const short* __restrict__ dbcT,
                 const short* __restrict__ xs, short* __restrict__ resy,
                 const float* __restrict__ A_log, const float* __restrict__ Dw,
                 const float* __restrict__ h0)
{
  const int lane = threadIdx.x & 63;
  const int grp = threadIdx.x >> 4, n = threadIdx.x & 15;
  const int ch = blockIdx.x * 16 + grp;          // ch = b*DI + d
  const int b = ch >> 11, d = ch & (DI - 1);
  const bool b3 = (lane & 8) != 0, b2 = (lane & 4) != 0,
             b1 = (lane & 2) != 0, b0 = (lane & 1) != 0;
  const float An2 = -__expf(A_log[d * NST + n]) * 1.44269504f;  // An * log2(e)
  const float Dd = Dw[d];
  float h = h0[(size_t)ch * NST + n];

  const size_t t0 = (size_t)b * L_;
  const short* dRow = dT   + (size_t)d * NTOK + t0;
  const short* bRow = dbcT + (size_t)n * NTOK + t0;
  const short* cRow = bRow + (size_t)NST * NTOK;
  const short* uLn  = xs   + (t0 + n) * DI + d;  // per-lane u row (lane n = step lv+n)
  short*       yCol = resy + (t0 + n) * DI + d;  // res read / y write, per-lane row

  auto LOADB = [&](int lv, bf16x8& t0v, bf16x8& t1v, bf16x8& B0v, bf16x8& B1v,
                   bf16x8& C0v, bf16x8& C1v, short& uo, short& rr) {
    t0v = *(const bf16x8*)(dRow + lv);
    t1v = *(const bf16x8*)(dRow + lv + 8);
    B0v = *(const bf16x8*)(bRow + lv);
    B1v = *(const bf16x8*)(bRow + lv + 8);
    C0v = *(const bf16x8*)(cRow + lv);
    C1v = *(const bf16x8*)(cRow + lv + 8);
    uo = uLn[(size_t)lv * DI];                   // u[lv+n][d], one load per lane
    rr = yCol[(size_t)lv * DI];
  };

  auto STEP = [&](int lv, bf16x8 t0v, bf16x8 t1v, bf16x8 B0v, bf16x8 B1v,
                  bf16x8 C0v, bf16x8 C1v, short uo, short rr) {
    const float uown = bf2f(uo);
    // ---- broadcast u[s] to all lanes of the group (LDS-pipe, no VMEM) ----
    float uf[16];
    uf[0]  = swz_bcast16<0>(uown);   uf[1]  = swz_bcast16<1>(uown);
    uf[2]  = swz_bcast16<2>(uown);   uf[3]  = swz_bcast16<3>(uown);
    uf[4]  = swz_bcast16<4>(uown);   uf[5]  = swz_bcast16<5>(uown);
    uf[6]  = swz_bcast16<6>(uown);   uf[7]  = swz_bcast16<7>(uown);
    uf[8]  = swz_bcast16<8>(uown);   uf[9]  = swz_bcast16<9>(uown);
    uf[10] = swz_bcast16<10>(uown);  uf[11] = swz_bcast16<11>(uown);
    uf[12] = swz_bcast16<12>(uown);  uf[13] = swz_bcast16<13>(uown);
    uf[14] = swz_bcast16<14>(uown);  uf[15] = swz_bcast16<15>(uown);
    // ---- precompute (independent of h) ----
    float dA[16], w[16];
#pragma unroll
    for (int s = 0; s < 16; s++) {
      float dt = bf2f(s < 8 ? t0v[s] : t1v[s - 8]);
      dA[s] = exp2f(dt * An2);
      w[s]  = dt * uf[s] * bf2f(s < 8 ? B0v[s] : B1v[s - 8]);
    }
    // ---- serial chain (16 FMAs) + per-state output term ----
    float p[16];
#pragma unroll
    for (int s = 0; s < 16; s++) {
      h = __builtin_fmaf(dA[s], h, w[s]);
      p[s] = h * bf2f(s < 8 ? C0v[s] : C1v[s - 8]);
    }
    // ---- butterfly transpose-reduce: lane n -> sum over states of p[n] ----
    float q8[8];
#pragma unroll
    for (int i = 0; i < 8; i++) {
      float keep = b3 ? p[i + 8] : p[i];
      float send = b3 ? p[i]     : p[i + 8];
      q8[i] = keep + swz_xor8(send);
    }
    float q4[4];
#pragma unroll
    for (int i = 0; i < 4; i++) {
      float keep = b2 ? q8[i + 4] : q8[i];
      float send = b2 ? q8[i]     : q8[i + 4];
      q4[i] = keep + swz_xor4(send);
    }
    float q2[2];
#pragma unroll
    for (int i = 0; i < 2; i++) {
      float keep = b1 ? q4[i + 2] : q4[i];
      float send = b1 ? q4[i]     : q4[i + 2];
      q2[i] = keep + qperm<0x4E>(send);       // quad_perm [2,3,0,1] = xor 2
    }
    float keep = b0 ? q2[1] : q2[0];
    float send = b0 ? q2[0] : q2[1];
    float ysum = keep + qperm<0xB1>(send);     // quad_perm [1,0,3,2] = xor 1
    // ---- skip term + gate + store (lane n owns step lv+n; uown = u[lv+n]) ----
    ysum = __builtin_fmaf(uown, Dd, ysum);
    float r = bf2f(rr);
    float yv = ysum * (r * sigmoidf_fast(r));
    yCol[(size_t)lv * DI] = f2bs(yv);
  };

  bf16x8 a0, a1, a2, a3, a4, a5; short ua, ra;
  bf16x8 c0, c1, c2, c3, c4, c5; short ub, rb;
  LOADB(0, a0, a1, a2, a3, a4, a5, ua, ra);
  for (int l = 0; l < L_; l += 32) {
    LOADB(l + 16, c0, c1, c2, c3, c4, c5, ub, rb);
    STEP(l, a0, a1, a2, a3, a4, a5, ua, ra);
    if (l + 32 < L_) LOADB(l + 32, a0, a1, a2, a3, a4, a5, ua, ra);
    STEP(l + 16, c0, c1, c2, c3, c4, c5, ub, rb);
  }
}

// ---------------------------------------------------------------------------
extern "C" void kernel_launch(void* const* d_in, const int* in_sizes, int n_in,
                              void* d_out, int out_size, void* d_ws, size_t ws_size,
                              hipStream_t stream)
{
  const float* u        = (const float*)d_in[0];
  const float* hiddens  = (const float*)d_in[1];
  const float* in_proj  = (const float*)d_in[2];
  const float* conv_w   = (const float*)d_in[3];
  const float* conv_b   = (const float*)d_in[4];
  const float* x_proj   = (const float*)d_in[5];   // (2048, 96)
  const float* dt_proj  = (const float*)d_in[6];   // (64, 2048)
  const float* dt_bias  = (const float*)d_in[7];
  const float* A_log    = (const float*)d_in[8];
  const float* Dw       = (const float*)d_in[9];
  const float* out_proj = (const float*)d_in[10];
  float* out = (float*)d_out;

  // workspace: ~74 MiB (under the previously proven 78 MiB)
  char* w = (char*)d_ws;
  short* Wt1  = (short*)w;                                 // in_proj^T (4096x1024), 8 MiB
  short* Wt4  = Wt1;                                       // out_proj^T reuses Wt1 after GEMM1
  w += (size_t)4096 * 1024 * 2;
  short* Wxp  = (short*)w; w += (size_t)128  * 2048 * 2;   // x_proj^T, padded to 128 rows
  short* dtw  = (short*)w; w += (size_t)2048 * 64   * 2;   // dt_proj^T  (2048 x 64)
  short* xbuf = (short*)w; w += (size_t)NTOK * DI   * 2;   // x (token-major) -> dT (chan-major)
  short* resy = (short*)w; w += (size_t)NTOK * DI   * 2;   // res (token-major) -> y in-place
  short* dbc  = (short*)w; w += (size_t)NTOK * DTR  * 2;   // dt_rank part, token-major (8192x64)
  short* dbcT = (short*)w; w += (size_t)32   * NTOK * 2;   // B|C transposed (32 x 8192)
  short* ub   = (short*)d_out;                             // u in bf16 (16 MiB, dead after GEMM1)
  short* xs   = (short*)d_out;                             // conv out borrows d_out after GEMM1
  short* dT   = xbuf;                                      // delta^T overlays dead x

  // prep: u->bf16 + in_proj^T + x_proj^T + dt_proj^T in ONE dispatch
  prep<<<4096 + 4096 + 192 + 128, 256, 0, stream>>>(u, ub, in_proj, Wt1,
                                                    x_proj, Wxp, dt_proj, dtw);

  // GEMM1: [x | res] = ub @ in_proj, split into xbuf / resy (token-major, ld=DI)
  gemm_bt<<<dim3(64, 32), 256, 0, stream>>>(ub, Wt1, xbuf, resy, nullptr,
                                            4096, 1024, 1024, 1024, DI, DI, 5);
  // conv + silu -> xs (token-major, in d_out) + out_proj^T -> Wt4 (rides along)
  conv_silu<<<NTOK + 2048, 256, 0, stream>>>(xbuf, conv_w, conv_b, xs, out_proj, Wt4);
  // GEMM2: dbc = xs @ x_proj; dt-rank cols token-major, B/C cols transposed to dbcT
  gemm_bt<<<dim3(64, 1), 256, 0, stream>>>(xs, Wxp, dbc, dbcT, nullptr,
                                           96, 2048, 2048, 2048, DTR, NTOK, 4);
  // GEMM3 (swapped operands): dT[d][t] = softplus(dtw[d,:] . dbc[t,:] + bias[d])
  gemm_bt<<<dim3(16, 64), 256, 0, stream>>>(dtw, dbc, dT, nullptr, dt_bias,
                                            NTOK, 64, 64, 64, NTOK, 0, 6);
  // selective scan + gated epilogue: y overwrites res in-place (token-major)
  scan_kernel<<<512, 256, 0, stream>>>(dT, dbcT, xs, resy, A_log, Dw, hiddens);
  // GEMM4: out = y @ out_proj  (8192 x 1024, f32 store)
  gemm_bt<<<dim3(64, 8), 256, 0, stream>>>(resy, Wt4, out, nullptr, nullptr,
                                           1024, 2048, 2048, 2048, 1024, 0, 2);
}

// Round 9
// 591.654 us; speedup vs baseline: 1.6479x; 1.0099x over previous
//
#include <hip/hip_runtime.h>
#include <hip/hip_bf16.h>
#include <cstddef>

#define B_   4
#define L_   2048
#define DM   1024
#define DI   2048
#define NST  16
#define DTR  64        // (1024+15)//16 = 64
#define NBC  96        // DTR + 2*NST
#define NTOK 8192      // B_*L_

using bf16 = __hip_bfloat16;
typedef __attribute__((ext_vector_type(8))) short bf16x8;
typedef __attribute__((ext_vector_type(4))) short s16x4;
typedef __attribute__((ext_vector_type(4))) float f32x4;

__device__ __forceinline__ float bf2f(short s) {
  unsigned u = ((unsigned)(unsigned short)s) << 16;
  float f; __builtin_memcpy(&f, &u, 4); return f;
}
__device__ __forceinline__ short f2bs(float f) {
  __hip_bfloat16 h = __float2bfloat16(f);
  short s; __builtin_memcpy(&s, &h, 2); return s;
}
__device__ __forceinline__ float sigmoidf_fast(float x) {
  return 1.f / (1.f + __expf(-x));
}

// async global->LDS, 16B per lane (dest must be wave-uniform base + lane*16)
#define GLD16(g, l) __builtin_amdgcn_global_load_lds( \
  (const __attribute__((address_space(1))) unsigned int*)(g), \
  (__attribute__((address_space(3))) unsigned int*)(l), 16, 0, 0)

// cross-lane xor shuffles for the 16-state butterfly reduce (within 32-lane halves)
__device__ __forceinline__ float swz_xor8(float x) {
  return __builtin_bit_cast(float,
    __builtin_amdgcn_ds_swizzle(__builtin_bit_cast(int, x), 0x201F)); // lane ^= 8
}
__device__ __forceinline__ float swz_xor4(float x) {
  return __builtin_bit_cast(float,
    __builtin_amdgcn_ds_swizzle(__builtin_bit_cast(int, x), 0x101F)); // lane ^= 4
}
template<int CTRL>
__device__ __forceinline__ float qperm(float x) {  // DPP quad_perm, full VALU rate
  return __builtin_bit_cast(float,
    __builtin_amdgcn_update_dpp(0, __builtin_bit_cast(int, x), CTRL, 0xf, 0xf, false));
}
// broadcast lane (group_base | S) to all 16 lanes of the group
template<int S>
__device__ __forceinline__ float swz_bcast16(float x) {
  return __builtin_bit_cast(float,
    __builtin_amdgcn_ds_swizzle(__builtin_bit_cast(int, x), (S << 5) | 0x10));
}

// ---------------------------------------------------------------------------
// shared transpose tile helper (f32 -> bf16, zero-pad)
// ---------------------------------------------------------------------------
__device__ __forceinline__ void transpose_tile(
    const float* __restrict__ in, short* __restrict__ out,
    int R, int Cc, int lin, int lout, int bx, int by, int tid, short (*t)[33])
{
  const int r0 = bx * 32, c0 = by * 32;
  const int tx = tid & 31, ty = tid >> 5;
#pragma unroll
  for (int i = 0; i < 4; i++) {
    int r = r0 + ty + i * 8;
    int c = c0 + tx;
    short v = 0;
    if (r < R && c < Cc) v = f2bs(in[(size_t)r * lin + c]);
    t[ty + i * 8][tx] = v;
  }
  __syncthreads();
#pragma unroll
  for (int i = 0; i < 4; i++) {
    int c = c0 + ty + i * 8;
    int r = r0 + tx;
    if (c < Cc && r < lout) out[(size_t)c * lout + r] = t[tx][ty + i * 8];
  }
}

// ---------------------------------------------------------------------------
// prep: one dispatch doing (a) u f32->bf16 convert, (b) in_proj^T,
// (c) x_proj^T, (d) dt_proj^T.  Linear block id -> region.
// ---------------------------------------------------------------------------
__global__ __launch_bounds__(256)
void prep(const float* __restrict__ u, short* __restrict__ ub,
          const float* __restrict__ in_proj, short* __restrict__ Wt1,
          const float* __restrict__ x_proj, short* __restrict__ Wxp,
          const float* __restrict__ dt_proj, short* __restrict__ dtw)
{
  __shared__ short t[32][33];
  int id = blockIdx.x;
  const int tid = threadIdx.x;
  if (id < 4096) {                       // u convert: 4096 blocks x 256 thr x 8
    const size_t i = ((size_t)id * 256 + tid) * 8;
    float4 a0 = *(const float4*)(u + i);
    float4 a1 = *(const float4*)(u + i + 4);
    union { bf16x8 v; short h[8]; } o;
    o.h[0] = f2bs(a0.x); o.h[1] = f2bs(a0.y); o.h[2] = f2bs(a0.z); o.h[3] = f2bs(a0.w);
    o.h[4] = f2bs(a1.x); o.h[5] = f2bs(a1.y); o.h[6] = f2bs(a1.z); o.h[7] = f2bs(a1.w);
    *(bf16x8*)(ub + i) = o.v;
    return;
  }
  id -= 4096;
  if (id < 4096) {                       // in_proj^T: grid (32,128)
    transpose_tile(in_proj, Wt1, 1024, 4096, 4096, 1024, id & 31, id >> 5, tid, t);
    return;
  }
  id -= 4096;
  if (id < 192) {                        // x_proj^T: grid (64,3)
    transpose_tile(x_proj, Wxp, 2048, 96, 96, 2048, id % 64, id / 64, tid, t);
    return;
  }
  id -= 192;                             // dt_proj^T: grid (2,64)
  transpose_tile(dt_proj, dtw, 64, 2048, 2048, 64, id & 1, id >> 1, tid, t);
}

// ---------------------------------------------------------------------------
// bf16 MFMA GEMM, C[M x N] = A[M x K] * Bt[N x K]^T.  128x128 tile, BK=64,
// 4 waves each 64x64 (4x4 of 16x16x32 MFMA).  global_load_lds (16B) staging,
// linear LDS dest with XOR-swizzled SOURCE col (T2 per rule #21).
// Block mapping: XCD chunk (bijective, i%8 -> XCD) THEN group-M swizzle
// (GM=8).  Requires nwg % 8 == 0 and gx % 8 == 0 (all call sites).
// mode 2: f32 token-major store.
// mode 4: col<DTR -> bf16 token-major to Cv (ldc); col>=DTR -> bf16 transposed to Cv2 (ldc2)
// mode 5: col<DI  -> bf16 token-major to Cv (ldc); col>=DI  -> token-major to Cv2 (ldc2)
// mode 6: softplus(v + bias[ROW]) -> bf16 row-major store (ldc)  [GEMM3 swapped form]
// ---------------------------------------------------------------------------
__global__ __launch_bounds__(256)
void gemm_bt(const short* __restrict__ A, const short* __restrict__ Bt,
             void* __restrict__ Cv, void* __restrict__ Cv2, const float* __restrict__ bias,
             int N, int K, int lda, int ldb, int ldc, int ldc2, int mode)
{
  __shared__ short As[128][64];
  __shared__ short Bs[128][64];
  const int gx = gridDim.x, gy = gridDim.y;
  const int nwg = gx * gy;
  const int lid = blockIdx.x + gx * blockIdx.y;
  const int cpx = nwg >> 3;                       // nwg % 8 == 0 for all call sites
  const int swz = (lid & 7) * cpx + (lid >> 3);   // XCD k owns swz in [k*cpx,(k+1)*cpx)
  const int nig = gy << 3;                        // tiles per m-group = GM(8) * gy
  const int grp_ = swz / nig;
  const int ing = swz - grp_ * nig;
  const int m0 = (grp_ * 8 + (ing & 7)) * 128;    // mt fastest within group of 8
  const int n0 = (ing >> 3) * 128;
  const int tid  = threadIdx.x;
  const int wave = tid >> 6, lane = tid & 63;
  const int wr = (wave >> 1) * 64, wc = (wave & 1) * 64;
  const int la = lane & 15, gq = lane >> 4;
  const int rs = (la & 7) << 3;                   // read-side XOR (row&7 == la&7)
  f32x4 acc[4][4] = {};

  for (int k0 = 0; k0 < K; k0 += 64) {
#pragma unroll
    for (int i = 0; i < 4; i++) {
      int idx = tid + i * 256;                    // 0..1023
      int row = idx >> 3, kc = (idx & 7) * 8;     // linear: addr = idx*16B
      int kcs = kc ^ ((row & 7) << 3);            // pre-swizzled global source col
      GLD16(A  + (size_t)(m0 + row) * lda + k0 + kcs, &As[row][kc]);
      GLD16(Bt + (size_t)(n0 + row) * ldb + k0 + kcs, &Bs[row][kc]);
    }
    __syncthreads();
#pragma unroll
    for (int kk = 0; kk < 2; kk++) {
      const int cl = (kk * 32 + gq * 8) ^ rs;     // swizzled read col
      bf16x8 af[4], bfr[4];
#pragma unroll
      for (int i = 0; i < 4; i++) af[i]  = *(const bf16x8*)(&As[wr + i * 16 + la][cl]);
#pragma unroll
      for (int j = 0; j < 4; j++) bfr[j] = *(const bf16x8*)(&Bs[wc + j * 16 + la][cl]);
#pragma unroll
      for (int i = 0; i < 4; i++)
#pragma unroll
        for (int j = 0; j < 4; j++)
          acc[i][j] = __builtin_amdgcn_mfma_f32_16x16x32_bf16(af[i], bfr[j], acc[i][j], 0, 0, 0);
    }
    __syncthreads();
  }

#pragma unroll
  for (int i = 0; i < 4; i++) {
    int rowb = m0 + wr + i * 16 + gq * 4;
#pragma unroll
    for (int j = 0; j < 4; j++) {
      int col = n0 + wc + j * 16 + la;
      if (col >= N) continue;
      if (mode == 2) {
#pragma unroll
        for (int r = 0; r < 4; r++)
          ((float*)Cv)[(size_t)(rowb + r) * ldc + col] = acc[i][j][r];
      } else if (mode == 4) {
        if (col < DTR) {
#pragma unroll
          for (int r = 0; r < 4; r++)
            ((short*)Cv)[(size_t)(rowb + r) * ldc + col] = f2bs(acc[i][j][r]);
        } else {
          s16x4 pk;
#pragma unroll
          for (int r = 0; r < 4; r++) pk[r] = f2bs(acc[i][j][r]);
          *(s16x4*)((short*)Cv2 + (size_t)(col - DTR) * ldc2 + rowb) = pk;
        }
      } else if (mode == 5) {
        short* base = (col < DI) ? (short*)Cv : (short*)Cv2;
        int c = (col < DI) ? col : col - DI;
        int ld = (col < DI) ? ldc : ldc2;
#pragma unroll
        for (int r = 0; r < 4; r++)
          base[(size_t)(rowb + r) * ld + c] = f2bs(acc[i][j][r]);
      } else if (mode == 6) {
        // softplus + per-ROW bias, row-major bf16 store (col = t is lane-consecutive)
#pragma unroll
        for (int r = 0; r < 4; r++) {
          float v = acc[i][j][r] + bias[rowb + r];
          float e = exp2f(v * 1.44269504f);
          v = (v > 20.f) ? v : 0.69314718f * __log2f(1.f + e);
          ((short*)Cv)[(size_t)(rowb + r) * ldc + col] = f2bs(v);
        }
      } else { // mode 0: plain bf16 token-major
#pragma unroll
        for (int r = 0; r < 4; r++)
          ((short*)Cv)[(size_t)(rowb + r) * ldc + col] = f2bs(acc[i][j][r]);
      }
    }
  }
}

// ---------------------------------------------------------------------------
// depthwise causal conv1d (k=4) + bias + SiLU (blocks < NTOK), plus
// out_proj^T transpose riding on blocks >= NTOK.
// ---------------------------------------------------------------------------
__global__ __launch_bounds__(256)
void conv_silu(const short* __restrict__ xb, const float* __restrict__ cw,
               const float* __restrict__ cb, short* __restrict__ xs,
               const float* __restrict__ op, short* __restrict__ Wt4)
{
  __shared__ short t[32][33];
  const int blk = blockIdx.x;
  if (blk >= NTOK) {                     // out_proj^T: 2048 blocks, grid (64,32)
    const int id2 = blk - NTOK;
    transpose_tile(op, Wt4, 2048, 1024, 1024, 2048, id2 & 63, id2 >> 6, threadIdx.x, t);
    return;
  }
  const int token = blk;
  const int l = token & (L_ - 1);
  const int d0 = threadIdx.x * 8;

  float w[32];
#pragma unroll
  for (int i = 0; i < 8; i++) {
    float4 tw = *(const float4*)(cw + (size_t)(d0 + i) * 4);
    w[i * 4 + 0] = tw.x; w[i * 4 + 1] = tw.y; w[i * 4 + 2] = tw.z; w[i * 4 + 3] = tw.w;
  }
  float acc[8];
  {
    float4 b0 = *(const float4*)(cb + d0);
    float4 b1 = *(const float4*)(cb + d0 + 4);
    acc[0] = b0.x; acc[1] = b0.y; acc[2] = b0.z; acc[3] = b0.w;
    acc[4] = b1.x; acc[5] = b1.y; acc[6] = b1.z; acc[7] = b1.w;
  }
#pragma unroll
  for (int j = 0; j < 4; j++) {
    int lj = l - 3 + j;
    if (lj >= 0) {
      bf16x8 xv = *(const bf16x8*)(xb + (size_t)(token - 3 + j) * DI + d0);
#pragma unroll
      for (int i = 0; i < 8; i++) acc[i] += w[i * 4 + j] * bf2f(xv[i]);
    }
  }
  union { bf16x8 v; short h[8]; } o;
#pragma unroll
  for (int i = 0; i < 8; i++) {
    float v = acc[i];
    o.h[i] = f2bs(v * sigmoidf_fast(v));
  }
  *(bf16x8*)(xs + (size_t)token * DI + d0) = o.v;
}

// ---------------------------------------------------------------------------
// selective scan, 16 lanes per (b,d) channel (one per state n), fused gating.
// R4-proven inner structure (48 VGPR, 2-deep ping-pong).  This round:
//  - 512-thread blocks (32 groups = 32 consecutive d) so the token-major
//    u/res/y accesses cover FULL 64B cache lines (was 32B -> 2x over-fetch)
//  - setprio(1) around the compute burst (independent blocks, phase-skewed
//    waves: the m191 attn-like regime where setprio measured +4-7%)
// ---------------------------------------------------------------------------
__global__ __launch_bounds__(512, 1)
void scan_kernel(const short* __restrict__ dT, const short* __restrict__ dbcT,
                 const short* __restrict__ xs, short* __restrict__ resy,
                 const float* __restrict__ A_log, const float* __restrict__ Dw,
                 const float* __restrict__ h0)
{
  const int lane = threadIdx.x & 63;
  const int grp = threadIdx.x >> 4, n = threadIdx.x & 15;
  const int ch = blockIdx.x * 32 + grp;          // ch = b*DI + d  (32 groups/block)
  const int b = ch >> 11, d = ch & (DI - 1);
  const bool b3 = (lane & 8) != 0, b2 = (lane & 4) != 0,
             b1 = (lane & 2) != 0, b0 = (lane & 1) != 0;
  const float An2 = -__expf(A_log[d * NST + n]) * 1.44269504f;  // An * log2(e)
  const float Dd = Dw[d];
  float h = h0[(size_t)ch * NST + n];

  const size_t t0 = (size_t)b * L_;
  const short* dRow = dT   + (size_t)d * NTOK + t0;
  const short* bRow = dbcT + (size_t)n * NTOK + t0;
  const short* cRow = bRow + (size_t)NST * NTOK;
  const short* uLn  = xs   + (t0 + n) * DI + d;  // per-lane u row (lane n = step lv+n)
  short*       yCol = resy + (t0 + n) * DI + d;  // res read / y write, per-lane row

  auto LOADB = [&](int lv, bf16x8& t0v, bf16x8& t1v, bf16x8& B0v, bf16x8& B1v,
                   bf16x8& C0v, bf16x8& C1v, short& uo, short& rr) {
    t0v = *(const bf16x8*)(dRow + lv);
    t1v = *(const bf16x8*)(dRow + lv + 8);
    B0v = *(const bf16x8*)(bRow + lv);
    B1v = *(const bf16x8*)(bRow + lv + 8);
    C0v = *(const bf16x8*)(cRow + lv);
    C1v = *(const bf16x8*)(cRow + lv + 8);
    uo = uLn[(size_t)lv * DI];                   // u[lv+n][d], one load per lane
    rr = yCol[(size_t)lv * DI];
  };

  auto STEP = [&](int lv, bf16x8 t0v, bf16x8 t1v, bf16x8 B0v, bf16x8 B1v,
                  bf16x8 C0v, bf16x8 C1v, short uo, short rr) {
    const float uown = bf2f(uo);
    __builtin_amdgcn_s_setprio(1);
    // ---- broadcast u[s] to all lanes of the group (LDS-pipe, no VMEM) ----
    float uf[16];
    uf[0]  = swz_bcast16<0>(uown);   uf[1]  = swz_bcast16<1>(uown);
    uf[2]  = swz_bcast16<2>(uown);   uf[3]  = swz_bcast16<3>(uown);
    uf[4]  = swz_bcast16<4>(uown);   uf[5]  = swz_bcast16<5>(uown);
    uf[6]  = swz_bcast16<6>(uown);   uf[7]  = swz_bcast16<7>(uown);
    uf[8]  = swz_bcast16<8>(uown);   uf[9]  = swz_bcast16<9>(uown);
    uf[10] = swz_bcast16<10>(uown);  uf[11] = swz_bcast16<11>(uown);
    uf[12] = swz_bcast16<12>(uown);  uf[13] = swz_bcast16<13>(uown);
    uf[14] = swz_bcast16<14>(uown);  uf[15] = swz_bcast16<15>(uown);
    // ---- precompute (independent of h) ----
    float dA[16], w[16];
#pragma unroll
    for (int s = 0; s < 16; s++) {
      float dt = bf2f(s < 8 ? t0v[s] : t1v[s - 8]);
      dA[s] = exp2f(dt * An2);
      w[s]  = dt * uf[s] * bf2f(s < 8 ? B0v[s] : B1v[s - 8]);
    }
    // ---- serial chain (16 FMAs) + per-state output term ----
    float p[16];
#pragma unroll
    for (int s = 0; s < 16; s++) {
      h = __builtin_fmaf(dA[s], h, w[s]);
      p[s] = h * bf2f(s < 8 ? C0v[s] : C1v[s - 8]);
    }
    // ---- butterfly transpose-reduce: lane n -> sum over states of p[n] ----
    float q8[8];
#pragma unroll
    for (int i = 0; i < 8; i++) {
      float keep = b3 ? p[i + 8] : p[i];
      float send = b3 ? p[i]     : p[i + 8];
      q8[i] = keep + swz_xor8(send);
    }
    float q4[4];
#pragma unroll
    for (int i = 0; i < 4; i++) {
      float keep = b2 ? q8[i + 4] : q8[i];
      float send = b2 ? q8[i]     : q8[i + 4];
      q4[i] = keep + swz_xor4(send);
    }
    float q2[2];
#pragma unroll
    for (int i = 0; i < 2; i++) {
      float keep = b1 ? q4[i + 2] : q4[i];
      float send = b1 ? q4[i]     : q4[i + 2];
      q2[i] = keep + qperm<0x4E>(send);       // quad_perm [2,3,0,1] = xor 2
    }
    float keep = b0 ? q2[1] : q2[0];
    float send = b0 ? q2[0] : q2[1];
    float ysum = keep + qperm<0xB1>(send);     // quad_perm [1,0,3,2] = xor 1
    // ---- skip term + gate (lane n owns step lv+n; uown = u[lv+n]) ----
    ysum = __builtin_fmaf(uown, Dd, ysum);
    float r = bf2f(rr);
    float yv = ysum * (r * sigmoidf_fast(r));
    __builtin_amdgcn_s_setprio(0);
    yCol[(size_t)lv * DI] = f2bs(yv);
  };

  bf16x8 a0, a1, a2, a3, a4, a5; short ua, ra;
  bf16x8 c0, c1, c2, c3, c4, c5; short ub, rb;
  LOADB(0, a0, a1, a2, a3, a4, a5, ua, ra);
  for (int l = 0; l < L_; l += 32) {
    LOADB(l + 16, c0, c1, c2, c3, c4, c5, ub, rb);
    STEP(l, a0, a1, a2, a3, a4, a5, ua, ra);
    if (l + 32 < L_) LOADB(l + 32, a0, a1, a2, a3, a4, a5, ua, ra);
    STEP(l + 16, c0, c1, c2, c3, c4, c5, ub, rb);
  }
}

// ---------------------------------------------------------------------------
extern "C" void kernel_launch(void* const* d_in, const int* in_sizes, int n_in,
                              void* d_out, int out_size, void* d_ws, size_t ws_size,
                              hipStream_t stream)
{
  const float* u        = (const float*)d_in[0];
  const float* hiddens  = (const float*)d_in[1];
  const float* in_proj  = (const float*)d_in[2];
  const float* conv_w   = (const float*)d_in[3];
  const float* conv_b   = (const float*)d_in[4];
  const float* x_proj   = (const float*)d_in[5];   // (2048, 96)
  const float* dt_proj  = (const float*)d_in[6];   // (64, 2048)
  const float* dt_bias  = (const float*)d_in[7];
  const float* A_log    = (const float*)d_in[8];
  const float* Dw       = (const float*)d_in[9];
  const float* out_proj = (const float*)d_in[10];
  float* out = (float*)d_out;

  // workspace: ~74 MiB (under the previously proven 78 MiB)
  char* w = (char*)d_ws;
  short* Wt1  = (short*)w;                                 // in_proj^T (4096x1024), 8 MiB
  short* Wt4  = Wt1;                                       // out_proj^T reuses Wt1 after GEMM1
  w += (size_t)4096 * 1024 * 2;
  short* Wxp  = (short*)w; w += (size_t)128  * 2048 * 2;   // x_proj^T, padded to 128 rows
  short* dtw  = (short*)w; w += (size_t)2048 * 64   * 2;   // dt_proj^T  (2048 x 64)
  short* xbuf = (short*)w; w += (size_t)NTOK * DI   * 2;   // x (token-major) -> dT (chan-major)
  short* resy = (short*)w; w += (size_t)NTOK * DI   * 2;   // res (token-major) -> y in-place
  short* dbc  = (short*)w; w += (size_t)NTOK * DTR  * 2;   // dt_rank part, token-major (8192x64)
  short* dbcT = (short*)w; w += (size_t)32   * NTOK * 2;   // B|C transposed (32 x 8192)
  short* ub   = (short*)d_out;                             // u in bf16 (16 MiB, dead after GEMM1)
  short* xs   = (short*)d_out;                             // conv out borrows d_out after GEMM1
  short* dT   = xbuf;                                      // delta^T overlays dead x

  // prep: u->bf16 + in_proj^T + x_proj^T + dt_proj^T in ONE dispatch
  prep<<<4096 + 4096 + 192 + 128, 256, 0, stream>>>(u, ub, in_proj, Wt1,
                                                    x_proj, Wxp, dt_proj, dtw);

  // GEMM1: [x | res] = ub @ in_proj, split into xbuf / resy (token-major, ld=DI)
  gemm_bt<<<dim3(64, 32), 256, 0, stream>>>(ub, Wt1, xbuf, resy, nullptr,
                                            4096, 1024, 1024, 1024, DI, DI, 5);
  // conv + silu -> xs (token-major, in d_out) + out_proj^T -> Wt4 (rides along)
  conv_silu<<<NTOK + 2048, 256, 0, stream>>>(xbuf, conv_w, conv_b, xs, out_proj, Wt4);
  // GEMM2: dbc = xs @ x_proj; dt-rank cols token-major, B/C cols transposed to dbcT
  gemm_bt<<<dim3(64, 1), 256, 0, stream>>>(xs, Wxp, dbc, dbcT, nullptr,
                                           96, 2048, 2048, 2048, DTR, NTOK, 4);
  // GEMM3 (swapped operands): dT[d][t] = softplus(dtw[d,:] . dbc[t,:] + bias[d])
  gemm_bt<<<dim3(16, 64), 256, 0, stream>>>(dtw, dbc, dT, nullptr, dt_bias,
                                            NTOK, 64, 64, 64, NTOK, 0, 6);
  // selective scan + gated epilogue: y overwrites res in-place (token-major)
  scan_kernel<<<256, 512, 0, stream>>>(dT, dbcT, xs, resy, A_log, Dw, hiddens);
  // GEMM4: out = y @ out_proj  (8192 x 1024, f32 store)
  gemm_bt<<<dim3(64, 8), 256, 0, stream>>>(resy, Wt4, out, nullptr, nullptr,
                                           1024, 2048, 2048, 2048, 1024, 0, 2);
}